// Round 4
// baseline (983.547 us; speedup 1.0000x reference)
//
#include <hip/hip_runtime.h>
#include <math.h>

// ---------------- problem constants ----------------
#define TOK   100352            // B * H * W  = 32*56*56  (= B_ * N = 2048*49)
#define OUTCH 19267584L         // TOK * 192, elements per output chunk (f32)
#define NWIN  2048
#define MLPR  12544             // MLP chunk rows (TOK / 8)

typedef __attribute__((ext_vector_type(4))) float f32x4;
typedef __attribute__((ext_vector_type(8))) short bf16x8;

__device__ __forceinline__ unsigned short f2bf(float f) {
    unsigned u = __builtin_bit_cast(unsigned, f);
    u += 0x7FFFu + ((u >> 16) & 1u);          // round-to-nearest-even
    return (unsigned short)(u >> 16);
}
__device__ __forceinline__ float bf2f(unsigned short s) {
    return __builtin_bit_cast(float, (unsigned)s << 16);
}

// ---------------- weight prep: transpose + bf16 cast ----------------
// layout in wt (bf16):
//  [0,110592)        qkv_wt [576][192]
//  [110592,147456)   proj_wt[192][192]
//  [147456,294912)   fc1_wt [768][192]
//  [294912,442368)   fc2_wt [192][768]
__global__ __launch_bounds__(256) void k_prep_w(const float* __restrict__ qkv_w,
                                                const float* __restrict__ proj_w,
                                                const float* __restrict__ fc1_w,
                                                const float* __restrict__ fc2_w,
                                                unsigned short* __restrict__ wt)
{
    int i = blockIdx.x * 256 + threadIdx.x;   // grid covers exactly 442368
    float v;
    if (i < 110592)       { int n = i / 192, k = i - n * 192;            v = qkv_w[k * 576 + n]; }
    else if (i < 147456)  { int j = i - 110592; int n = j / 192, k = j - n * 192; v = proj_w[k * 192 + n]; }
    else if (i < 294912)  { int j = i - 147456; int n = j / 192, k = j - n * 192; v = fc1_w[k * 768 + n]; }
    else                  { int j = i - 294912; int n = j / 768, k = j - n * 768; v = fc2_w[k * 192 + n]; }
    wt[i] = f2bf(v);
}

// ---------------- LN1 + roll(-3,-3) + window partition -> bf16 win ----------------
__global__ __launch_bounds__(256) void k_ln1(const float* __restrict__ x,
                                             const float* __restrict__ g,
                                             const float* __restrict__ b,
                                             unsigned short* __restrict__ win)
{
    int lane = threadIdx.x & 63;
    int t = blockIdx.x * 4 + (threadIdx.x >> 6);      // window-token index
    int w = t / 49, n = t - w * 49;
    int bb = w >> 6, widx = w & 63;
    int wi = widx >> 3, wj = widx & 7;
    int r = n / 7, s = n - r * 7;
    int hh = wi * 7 + r + 3; if (hh >= 56) hh -= 56;  // roll(-SHIFT): rolled(h)=orig(h+3)
    int ww = wj * 7 + s + 3; if (ww >= 56) ww -= 56;
    const float* src = x + ((long)(bb * 56 + hh) * 56 + ww) * 192;
    float v0 = src[lane], v1 = src[lane + 64], v2 = src[lane + 128];
    float sum = v0 + v1 + v2;
    float sq  = v0 * v0 + v1 * v1 + v2 * v2;
    #pragma unroll
    for (int o = 32; o; o >>= 1) { sum += __shfl_xor(sum, o); sq += __shfl_xor(sq, o); }
    float mu = sum * (1.f / 192.f);
    float rs = rsqrtf(sq * (1.f / 192.f) - mu * mu + 1e-5f);
    unsigned short* dst = win + (long)t * 192;
    dst[lane]       = f2bf((v0 - mu) * rs * g[lane]       + b[lane]);
    dst[lane + 64]  = f2bf((v1 - mu) * rs * g[lane + 64]  + b[lane + 64]);
    dst[lane + 128] = f2bf((v2 - mu) * rs * g[lane + 128] + b[lane + 128]);
}

// ---------------- LN2: f32 xo -> bf16 h2 ----------------
__global__ __launch_bounds__(256) void k_ln2(const float* __restrict__ xo,
                                             const float* __restrict__ g,
                                             const float* __restrict__ b,
                                             unsigned short* __restrict__ h2)
{
    int lane = threadIdx.x & 63;
    long t = (long)blockIdx.x * 4 + (threadIdx.x >> 6);
    const float* src = xo + t * 192;
    float v0 = src[lane], v1 = src[lane + 64], v2 = src[lane + 128];
    float sum = v0 + v1 + v2;
    float sq  = v0 * v0 + v1 * v1 + v2 * v2;
    #pragma unroll
    for (int o = 32; o; o >>= 1) { sum += __shfl_xor(sum, o); sq += __shfl_xor(sq, o); }
    float mu = sum * (1.f / 192.f);
    float rs = rsqrtf(sq * (1.f / 192.f) - mu * mu + 1e-5f);
    unsigned short* dst = h2 + t * 192;
    dst[lane]       = f2bf((v0 - mu) * rs * g[lane]       + b[lane]);
    dst[lane + 64]  = f2bf((v1 - mu) * rs * g[lane + 64]  + b[lane + 64]);
    dst[lane + 128] = f2bf((v2 - mu) * rs * g[lane + 128] + b[lane + 128]);
}

// ---------------- shared GEMM main loop ----------------
// BM=128, BN=64, staged BK=192. A: [M][lda] bf16 row-major. Bt: [N][ldb] bf16 (transposed weights).
// LDS tiles XOR-swizzled (byte ^= (row&7)<<4) to keep ds_read_b128 conflict-free at 384 B row stride.
template<int KTOT>
__device__ __forceinline__ void gemm_tile(const unsigned short* __restrict__ A, int lda,
                                          const unsigned short* __restrict__ Bt, int ldb,
                                          int m0, int n0,
                                          unsigned short* lA, unsigned short* lB,
                                          f32x4 acc[4][2])
{
    const int tid = threadIdx.x, lane = tid & 63, wid = tid >> 6;
    const int wr = wid >> 1, wc = wid & 1;
    #pragma unroll
    for (int mi = 0; mi < 4; mi++)
        #pragma unroll
        for (int ni = 0; ni < 2; ni++) acc[mi][ni] = (f32x4){0.f, 0.f, 0.f, 0.f};

    for (int kt = 0; kt < KTOT; kt += 192) {
        __syncthreads();
        #pragma unroll
        for (int c = tid; c < 128 * 24; c += 256) {     // A: 128 rows x 24 16B-chunks
            int row = c / 24, k16 = c - row * 24;
            bf16x8 v = *(const bf16x8*)(A + (long)(m0 + row) * lda + kt + k16 * 8);
            *(bf16x8*)((char*)lA + row * 384 + ((k16 * 16) ^ ((row & 7) << 4))) = v;
        }
        #pragma unroll
        for (int c = tid; c < 64 * 24; c += 256) {      // B: 64 rows x 24 chunks
            int row = c / 24, k16 = c - row * 24;
            bf16x8 v = *(const bf16x8*)(Bt + (long)(n0 + row) * ldb + kt + k16 * 8);
            *(bf16x8*)((char*)lB + row * 384 + ((k16 * 16) ^ ((row & 7) << 4))) = v;
        }
        __syncthreads();
        #pragma unroll
        for (int ks = 0; ks < 6; ks++) {                // 192 / 32
            int kb = ks * 64 + ((lane >> 4) << 4);      // byte offset of this lane-group's 8 k-elems
            bf16x8 bfr[2];
            #pragma unroll
            for (int ni = 0; ni < 2; ni++) {
                int row = wc * 32 + ni * 16 + (lane & 15);
                bfr[ni] = *(const bf16x8*)((char*)lB + row * 384 + (kb ^ ((row & 7) << 4)));
            }
            #pragma unroll
            for (int mi = 0; mi < 4; mi++) {
                int row = wr * 64 + mi * 16 + (lane & 15);
                bf16x8 afr = *(const bf16x8*)((char*)lA + row * 384 + (kb ^ ((row & 7) << 4)));
                #pragma unroll
                for (int ni = 0; ni < 2; ni++)
                    acc[mi][ni] = __builtin_amdgcn_mfma_f32_16x16x32_bf16(afr, bfr[ni], acc[mi][ni], 0, 0, 0);
            }
        }
    }
}

// ---------------- QKV GEMM: win @ qkv_wt + b -> q/k/v chunks of d_out (f32) ----------------
__global__ __launch_bounds__(256) void k_gemm_qkv(const unsigned short* __restrict__ A,
                                                  const unsigned short* __restrict__ Bt,
                                                  const float* __restrict__ bias,
                                                  float* __restrict__ outq)
{
    __shared__ unsigned short lA[128 * 192];
    __shared__ unsigned short lB[64 * 192];
    f32x4 acc[4][2];
    int m0 = blockIdx.y * 128, n0 = blockIdx.x * 64;
    gemm_tile<192>(A, 192, Bt, 192, m0, n0, lA, lB, acc);
    int lane = threadIdx.x & 63, wid = threadIdx.x >> 6;
    int wr = wid >> 1, wc = wid & 1;
    #pragma unroll
    for (int mi = 0; mi < 4; mi++)
        #pragma unroll
        for (int ni = 0; ni < 2; ni++) {
            int gcol = n0 + wc * 32 + ni * 16 + (lane & 15);
            int ch = gcol / 192; int cc = gcol - ch * 192;
            float bv = bias[gcol];
            float* base = outq + (long)ch * OUTCH + cc;
            #pragma unroll
            for (int r = 0; r < 4; r++) {
                long grow = m0 + wr * 64 + mi * 16 + ((lane >> 4) << 2) + r;
                base[grow * 192] = acc[mi][ni][r] + bv;
            }
        }
}

// ---------------- proj GEMM + window reverse + roll(+3,+3) + residual -> xo f32 (d_out ch0) ---------
__global__ __launch_bounds__(256) void k_gemm_proj(const unsigned short* __restrict__ A,
                                                   const unsigned short* __restrict__ Bt,
                                                   const float* __restrict__ bias,
                                                   const float* __restrict__ x,
                                                   float* __restrict__ xo)
{
    __shared__ unsigned short lA[128 * 192];
    __shared__ unsigned short lB[64 * 192];
    f32x4 acc[4][2];
    int m0 = blockIdx.y * 128, n0 = blockIdx.x * 64;
    gemm_tile<192>(A, 192, Bt, 192, m0, n0, lA, lB, acc);
    int lane = threadIdx.x & 63, wid = threadIdx.x >> 6;
    int wr = wid >> 1, wc = wid & 1;
    #pragma unroll
    for (int mi = 0; mi < 4; mi++)
        #pragma unroll
        for (int ni = 0; ni < 2; ni++) {
            int gcol = n0 + wc * 32 + ni * 16 + (lane & 15);
            float bv = bias[gcol];
            #pragma unroll
            for (int r = 0; r < 4; r++) {
                int t = m0 + wr * 64 + mi * 16 + ((lane >> 4) << 2) + r;   // window token
                int w = t / 49, n = t - w * 49;
                int bb = w >> 6, widx = w & 63;
                int wi = widx >> 3, wj = widx & 7;
                int rr = n / 7, ss = n - rr * 7;
                int ho = wi * 7 + rr + 3; if (ho >= 56) ho -= 56;          // roll(+SHIFT)
                int wo = wj * 7 + ss + 3; if (wo >= 56) wo -= 56;
                long tp = ((long)(bb * 56 + ho) * 56 + wo);
                xo[tp * 192 + gcol] = x[tp * 192 + gcol] + acc[mi][ni][r] + bv;
            }
        }
}

// ---------------- FC1 + exact GELU -> G (bf16 ws chunk) ----------------
__global__ __launch_bounds__(256) void k_gemm_fc1(const unsigned short* __restrict__ A,
                                                  const unsigned short* __restrict__ Bt,
                                                  const float* __restrict__ bias,
                                                  unsigned short* __restrict__ G)
{
    __shared__ unsigned short lA[128 * 192];
    __shared__ unsigned short lB[64 * 192];
    f32x4 acc[4][2];
    int m0 = blockIdx.y * 128, n0 = blockIdx.x * 64;
    gemm_tile<192>(A, 192, Bt, 192, m0, n0, lA, lB, acc);
    int lane = threadIdx.x & 63, wid = threadIdx.x >> 6;
    int wr = wid >> 1, wc = wid & 1;
    #pragma unroll
    for (int mi = 0; mi < 4; mi++)
        #pragma unroll
        for (int ni = 0; ni < 2; ni++) {
            int gcol = n0 + wc * 32 + ni * 16 + (lane & 15);
            float bv = bias[gcol];
            #pragma unroll
            for (int r = 0; r < 4; r++) {
                long grow = m0 + wr * 64 + mi * 16 + ((lane >> 4) << 2) + r;
                float v = acc[mi][ni][r] + bv;
                float ge = 0.5f * v * (1.f + erff(v * 0.70710678118654752f));
                G[grow * 768 + gcol] = f2bf(ge);
            }
        }
}

// ---------------- FC2 + residual (in-place on f32 xo chunk of d_out) ----------------
__global__ __launch_bounds__(256) void k_gemm_fc2(const unsigned short* __restrict__ A,
                                                  const unsigned short* __restrict__ Bt,
                                                  const float* __restrict__ bias,
                                                  float* __restrict__ xo)
{
    __shared__ unsigned short lA[128 * 192];
    __shared__ unsigned short lB[64 * 192];
    f32x4 acc[4][2];
    int m0 = blockIdx.y * 128, n0 = blockIdx.x * 64;
    gemm_tile<768>(A, 768, Bt, 768, m0, n0, lA, lB, acc);
    int lane = threadIdx.x & 63, wid = threadIdx.x >> 6;
    int wr = wid >> 1, wc = wid & 1;
    #pragma unroll
    for (int mi = 0; mi < 4; mi++)
        #pragma unroll
        for (int ni = 0; ni < 2; ni++) {
            int gcol = n0 + wc * 32 + ni * 16 + (lane & 15);
            float bv = bias[gcol];
            #pragma unroll
            for (int r = 0; r < 4; r++) {
                long grow = m0 + wr * 64 + mi * 16 + ((lane >> 4) << 2) + r;
                xo[grow * 192 + gcol] += acc[mi][ni][r] + bv;
            }
        }
}

// ---------------- attention: one block (6 waves = 6 heads) per window ----------------
// Inputs q/k/v are f32 (d_out chunks); output bf16 to ws.
// LDS: Ks 24576 + Vt 24576 + ATT 77616 = 126,768 B
__global__ __launch_bounds__(384) void k_attn(const float* __restrict__ qg,
                                              const float* __restrict__ kg,
                                              const float* __restrict__ vg,
                                              const float* __restrict__ rpb,
                                              const float* __restrict__ plw,
                                              const float* __restrict__ plb,
                                              const float* __restrict__ pww,
                                              const float* __restrict__ pwb,
                                              unsigned short* __restrict__ aout)
{
    __shared__ unsigned short Ks[6][64][32];   // K rows padded to 64 (zeros)
    __shared__ unsigned short Vt[6][32][64];   // V transposed [d][n], XOR-swizzled, n padded w/ zeros
    __shared__ float ATT[6][49][66];           // scores; cols [49,66) zeroed (PV reads k up to 63)

    int w = blockIdx.x, widx = w & 63;
    int tid = threadIdx.x, lane = tid & 63, h = tid >> 6;   // wave id == head
    const long base = (long)w * 49 * 192;

    // ---- stage K (bf16), V (transposed+swizzled bf16), zero ATT pad cols ----
    for (int c = tid; c < 1536; c += 384) {                 // 6 heads * 64 rows * 4 chunks of 8
        int hh = c >> 8, rem = c & 255, row = rem >> 2, k16 = rem & 3;
        float kv[8], vv[8];
        #pragma unroll
        for (int j = 0; j < 8; j++) { kv[j] = 0.f; vv[j] = 0.f; }
        if (row < 49) {
            const float* kp = kg + base + row * 192 + hh * 32 + k16 * 8;
            const float* vp = vg + base + row * 192 + hh * 32 + k16 * 8;
            #pragma unroll
            for (int j = 0; j < 8; j++) { kv[j] = kp[j]; vv[j] = vp[j]; }
        }
        bf16x8 k8;
        #pragma unroll
        for (int j = 0; j < 8; j++) k8[j] = (short)f2bf(kv[j]);
        *(bf16x8*)&Ks[hh][row][k16 * 8] = k8;
        #pragma unroll
        for (int j = 0; j < 8; j++) {
            int d = k16 * 8 + j;
            int byteoff = (hh * 32 + d) * 128 + ((row * 2) ^ ((d & 7) << 4));
            *(unsigned short*)((char*)Vt + byteoff) = f2bf(vv[j]);
        }
    }
    for (int c = tid; c < 6 * 49 * 17; c += 384) {          // zero ATT[:, :, 49..65]
        int g2 = c / (49 * 17), rem = c - g2 * (49 * 17);
        int m = rem / 17, n = 49 + (rem - m * 17);
        ATT[g2][m][n] = 0.f;
    }
    __syncthreads();

    // ---- QK^T (per head) ----
    bf16x8 qfr[4];
    #pragma unroll
    for (int mi = 0; mi < 4; mi++) {
        int m = mi * 16 + (lane & 15); int mm = m < 49 ? m : 48;
        const float* qp = qg + base + mm * 192 + h * 32 + ((lane >> 4) << 3);
        #pragma unroll
        for (int j = 0; j < 8; j++) qfr[mi][j] = (short)f2bf(qp[j]);
    }
    f32x4 sa[4][4];
    #pragma unroll
    for (int ni = 0; ni < 4; ni++) {
        bf16x8 kfr = *(const bf16x8*)&Ks[h][ni * 16 + (lane & 15)][(lane >> 4) << 3];
        #pragma unroll
        for (int mi = 0; mi < 4; mi++)
            sa[mi][ni] = __builtin_amdgcn_mfma_f32_16x16x32_bf16(qfr[mi], kfr, (f32x4){0.f, 0.f, 0.f, 0.f}, 0, 0, 0);
    }
    const float scale = 0.17677669529663687f;   // 32^-0.5
    #pragma unroll
    for (int mi = 0; mi < 4; mi++)
        #pragma unroll
        for (int ni = 0; ni < 4; ni++)
            #pragma unroll
            for (int r = 0; r < 4; r++) {
                int m = mi * 16 + ((lane >> 4) << 2) + r, n = ni * 16 + (lane & 15);
                if (m < 49 && n < 49) {
                    int rq = m / 7, cq = m - rq * 7, rk = n / 7, ck = n - rk * 7;
                    int ridx = (rq - rk + 6) * 13 + (cq - ck + 6);
                    ATT[h][m][n] = sa[mi][ni][r] * scale + rpb[ridx * 6 + h];
                }
            }
    __syncthreads();

    // ---- pl head-mix + shift mask (in place) ----
    int wi = widx >> 3, wj = widx & 7;
    for (int p = tid; p < 2401; p += 384) {
        int m = p / 49, n = p - m * 49;
        float a[6];
        #pragma unroll
        for (int g2 = 0; g2 < 6; g2++) a[g2] = ATT[g2][m][n];
        int rq = m / 7, cq = m - rq * 7, rk = n / 7, ck = n - rk * 7;
        int ghq = wi * 7 + rq, gwq = wj * 7 + cq, ghk = wi * 7 + rk, gwk = wj * 7 + ck;
        int regq = (ghq < 49 ? 0 : (ghq < 53 ? 1 : 2)) * 3 + (gwq < 49 ? 0 : (gwq < 53 ? 1 : 2));
        int regk = (ghk < 49 ? 0 : (ghk < 53 ? 1 : 2)) * 3 + (gwk < 49 ? 0 : (gwk < 53 ? 1 : 2));
        float msk = (regq != regk) ? -100.f : 0.f;
        #pragma unroll
        for (int g2 = 0; g2 < 6; g2++) {
            float v = plb[g2] + msk;
            #pragma unroll
            for (int h2 = 0; h2 < 6; h2++) v += a[h2] * plw[h2 * 6 + g2];
            ATT[g2][m][n] = v;
        }
    }
    __syncthreads();

    // ---- softmax over rows (wave per row-task) ----
    for (int task = h; task < 294; task += 6) {
        int g2 = task / 49, m = task - g2 * 49;
        float v = (lane < 49) ? ATT[g2][m][lane] : -3.4e38f;
        float mx = v;
        #pragma unroll
        for (int o = 32; o; o >>= 1) mx = fmaxf(mx, __shfl_xor(mx, o));
        float e = (lane < 49) ? __expf(v - mx) : 0.f;
        float sm = e;
        #pragma unroll
        for (int o = 32; o; o >>= 1) sm += __shfl_xor(sm, o);
        if (lane < 49) ATT[g2][m][lane] = e / sm;
    }
    __syncthreads();

    // ---- pw head-mix (in place) ----
    for (int p = tid; p < 2401; p += 384) {
        int m = p / 49, n = p - m * 49;
        float a[6];
        #pragma unroll
        for (int g2 = 0; g2 < 6; g2++) a[g2] = ATT[g2][m][n];
        #pragma unroll
        for (int g2 = 0; g2 < 6; g2++) {
            float v = pwb[g2];
            #pragma unroll
            for (int h2 = 0; h2 < 6; h2++) v += a[h2] * pww[h2 * 6 + g2];
            ATT[g2][m][n] = v;
        }
    }
    __syncthreads();

    // ---- PV (per head): out[m][d] = sum_n soft[m][n] * V[n][d] ----
    f32x4 oa[4][2];
    #pragma unroll
    for (int mi = 0; mi < 4; mi++)
        #pragma unroll
        for (int ni = 0; ni < 2; ni++) oa[mi][ni] = (f32x4){0.f, 0.f, 0.f, 0.f};
    #pragma unroll
    for (int kst = 0; kst < 2; kst++) {
        bf16x8 vfr[2];
        #pragma unroll
        for (int ni = 0; ni < 2; ni++) {
            int d = ni * 16 + (lane & 15);
            int byteoff = (h * 32 + d) * 128 + ((kst * 64 + ((lane >> 4) << 4)) ^ ((d & 7) << 4));
            vfr[ni] = *(const bf16x8*)((char*)Vt + byteoff);
        }
        #pragma unroll
        for (int mi = 0; mi < 4; mi++) {
            int m = mi * 16 + (lane & 15); int mm = m < 49 ? m : 48;
            const float* ap = &ATT[h][mm][kst * 32 + ((lane >> 4) << 3)];
            bf16x8 afr;
            #pragma unroll
            for (int j = 0; j < 8; j++) afr[j] = (short)f2bf(ap[j]);
            #pragma unroll
            for (int ni = 0; ni < 2; ni++)
                oa[mi][ni] = __builtin_amdgcn_mfma_f32_16x16x32_bf16(afr, vfr[ni], oa[mi][ni], 0, 0, 0);
        }
    }
    #pragma unroll
    for (int mi = 0; mi < 4; mi++)
        #pragma unroll
        for (int ni = 0; ni < 2; ni++)
            #pragma unroll
            for (int r = 0; r < 4; r++) {
                int m = mi * 16 + ((lane >> 4) << 2) + r, d = ni * 16 + (lane & 15);
                if (m < 49) aout[base + m * 192 + h * 32 + d] = f2bf(oa[mi][ni][r]);
            }
}

// ---------------- launcher ----------------
extern "C" void kernel_launch(void* const* d_in, const int* in_sizes, int n_in,
                              void* d_out, int out_size, void* d_ws, size_t ws_size,
                              hipStream_t stream)
{
    const float* x      = (const float*)d_in[0];
    const float* n1g    = (const float*)d_in[1];
    const float* n1b    = (const float*)d_in[2];
    const float* qkv_w  = (const float*)d_in[3];
    const float* qkv_b  = (const float*)d_in[4];
    const float* proj_w = (const float*)d_in[5];
    const float* proj_b = (const float*)d_in[6];
    const float* rpb    = (const float*)d_in[7];
    const float* pl_w   = (const float*)d_in[8];
    const float* pl_b   = (const float*)d_in[9];
    const float* pw_w   = (const float*)d_in[10];
    const float* pw_b   = (const float*)d_in[11];
    const float* n2g    = (const float*)d_in[12];
    const float* n2b    = (const float*)d_in[13];
    const float* fc1_w  = (const float*)d_in[14];
    const float* fc1_b  = (const float*)d_in[15];
    const float* fc2_w  = (const float*)d_in[16];
    const float* fc2_b  = (const float*)d_in[17];

    float* out   = (float*)d_out;   // f32: [xo | q | k | v], each OUTCH elements
    float* out_q = out + OUTCH;
    float* out_k = out + 2 * OUTCH;
    float* out_v = out + 3 * OUTCH;

    // ws: bufT 38,535,168 (bf16 TOKx192, time-shared win/attn-out/h2)
    //     bufG 19,267,584 (bf16 MLPRx768) | bufW 884,736  => total 58,687,488 B
    char* ws = (char*)d_ws;
    unsigned short* bufT = (unsigned short*)ws;
    unsigned short* bufG = (unsigned short*)(ws + 38535168);
    unsigned short* bufW = (unsigned short*)(ws + 57802752);

    k_prep_w<<<1728, 256, 0, stream>>>(qkv_w, proj_w, fc1_w, fc2_w, bufW);
    k_ln1<<<25088, 256, 0, stream>>>(x, n1g, n1b, bufT);                      // bufT = win
    k_gemm_qkv<<<dim3(9, 784), 256, 0, stream>>>(bufT, bufW, qkv_b, out_q);   // q/k/v f32
    k_attn<<<NWIN, 384, 0, stream>>>(out_q, out_k, out_v,
                                     rpb, pl_w, pl_b, pw_w, pw_b, bufT);      // bufT = attn out
    k_gemm_proj<<<dim3(3, 784), 256, 0, stream>>>(bufT, bufW + 110592, proj_b, x, out); // out[0:OUTCH] = pre-MLP xo
    k_ln2<<<25088, 256, 0, stream>>>(out, n2g, n2b, bufT);                    // bufT = h2
    for (int c = 0; c < 8; c++) {
        long off = (long)c * MLPR * 192;
        k_gemm_fc1<<<dim3(12, 98), 256, 0, stream>>>(bufT + off, bufW + 147456, fc1_b, bufG);
        k_gemm_fc2<<<dim3(3, 98), 256, 0, stream>>>(bufG, bufW + 294912, fc2_b, out + off);
    }
}

// Round 5
// 779.243 us; speedup vs baseline: 1.2622x; 1.2622x over previous
//
#include <hip/hip_runtime.h>
#include <math.h>

// ---------------- problem constants ----------------
#define TOK   100352            // B * H * W  = 32*56*56  (= B_ * N = 2048*49)
#define OUTCH 19267584L         // TOK * 192, elements per output chunk (f32)
#define NWIN  2048
#define MLPR  12544             // MLP chunk rows (TOK / 8)

typedef __attribute__((ext_vector_type(4))) float f32x4;
typedef __attribute__((ext_vector_type(8))) short bf16x8;

__device__ __forceinline__ unsigned short f2bf(float f) {
    unsigned u = __builtin_bit_cast(unsigned, f);
    u += 0x7FFFu + ((u >> 16) & 1u);          // round-to-nearest-even
    return (unsigned short)(u >> 16);
}
__device__ __forceinline__ float bf2f(unsigned short s) {
    return __builtin_bit_cast(float, (unsigned)s << 16);
}

// ---------------- weight prep: transpose + bf16 cast ----------------
// layout in wt (bf16):
//  [0,110592)        qkv_wt [576][192]
//  [110592,147456)   proj_wt[192][192]
//  [147456,294912)   fc1_wt [768][192]
//  [294912,442368)   fc2_wt [192][768]
__global__ __launch_bounds__(256) void k_prep_w(const float* __restrict__ qkv_w,
                                                const float* __restrict__ proj_w,
                                                const float* __restrict__ fc1_w,
                                                const float* __restrict__ fc2_w,
                                                unsigned short* __restrict__ wt)
{
    int i = blockIdx.x * 256 + threadIdx.x;   // grid covers exactly 442368
    float v;
    if (i < 110592)       { int n = i / 192, k = i - n * 192;            v = qkv_w[k * 576 + n]; }
    else if (i < 147456)  { int j = i - 110592; int n = j / 192, k = j - n * 192; v = proj_w[k * 192 + n]; }
    else if (i < 294912)  { int j = i - 147456; int n = j / 192, k = j - n * 192; v = fc1_w[k * 768 + n]; }
    else                  { int j = i - 294912; int n = j / 768, k = j - n * 768; v = fc2_w[k * 192 + n]; }
    wt[i] = f2bf(v);
}

// ---------------- LN1 + roll(-3,-3) + window partition -> bf16 win ----------------
__global__ __launch_bounds__(256) void k_ln1(const float* __restrict__ x,
                                             const float* __restrict__ g,
                                             const float* __restrict__ b,
                                             unsigned short* __restrict__ win)
{
    int lane = threadIdx.x & 63;
    int t = blockIdx.x * 4 + (threadIdx.x >> 6);      // window-token index
    int w = t / 49, n = t - w * 49;
    int bb = w >> 6, widx = w & 63;
    int wi = widx >> 3, wj = widx & 7;
    int r = n / 7, s = n - r * 7;
    int hh = wi * 7 + r + 3; if (hh >= 56) hh -= 56;  // roll(-SHIFT): rolled(h)=orig(h+3)
    int ww = wj * 7 + s + 3; if (ww >= 56) ww -= 56;
    const float* src = x + ((long)(bb * 56 + hh) * 56 + ww) * 192;
    float v0 = src[lane], v1 = src[lane + 64], v2 = src[lane + 128];
    float sum = v0 + v1 + v2;
    float sq  = v0 * v0 + v1 * v1 + v2 * v2;
    #pragma unroll
    for (int o = 32; o; o >>= 1) { sum += __shfl_xor(sum, o); sq += __shfl_xor(sq, o); }
    float mu = sum * (1.f / 192.f);
    float rs = rsqrtf(sq * (1.f / 192.f) - mu * mu + 1e-5f);
    unsigned short* dst = win + (long)t * 192;
    dst[lane]       = f2bf((v0 - mu) * rs * g[lane]       + b[lane]);
    dst[lane + 64]  = f2bf((v1 - mu) * rs * g[lane + 64]  + b[lane + 64]);
    dst[lane + 128] = f2bf((v2 - mu) * rs * g[lane + 128] + b[lane + 128]);
}

// ---------------- LN2: f32 xo -> bf16 h2 ----------------
__global__ __launch_bounds__(256) void k_ln2(const float* __restrict__ xo,
                                             const float* __restrict__ g,
                                             const float* __restrict__ b,
                                             unsigned short* __restrict__ h2)
{
    int lane = threadIdx.x & 63;
    long t = (long)blockIdx.x * 4 + (threadIdx.x >> 6);
    const float* src = xo + t * 192;
    float v0 = src[lane], v1 = src[lane + 64], v2 = src[lane + 128];
    float sum = v0 + v1 + v2;
    float sq  = v0 * v0 + v1 * v1 + v2 * v2;
    #pragma unroll
    for (int o = 32; o; o >>= 1) { sum += __shfl_xor(sum, o); sq += __shfl_xor(sq, o); }
    float mu = sum * (1.f / 192.f);
    float rs = rsqrtf(sq * (1.f / 192.f) - mu * mu + 1e-5f);
    unsigned short* dst = h2 + t * 192;
    dst[lane]       = f2bf((v0 - mu) * rs * g[lane]       + b[lane]);
    dst[lane + 64]  = f2bf((v1 - mu) * rs * g[lane + 64]  + b[lane + 64]);
    dst[lane + 128] = f2bf((v2 - mu) * rs * g[lane + 128] + b[lane + 128]);
}

// ---------------- shared GEMM main loop ----------------
// BM=128, BN=64, staged BK=192. A: [M][lda] bf16 row-major. Bt: [N][ldb] bf16 (transposed weights).
// LDS tiles XOR-swizzled (byte ^= (row&7)<<4) to keep ds_read_b128 conflict-free at 384 B row stride.
template<int KTOT>
__device__ __forceinline__ void gemm_tile(const unsigned short* __restrict__ A, int lda,
                                          const unsigned short* __restrict__ Bt, int ldb,
                                          int m0, int n0,
                                          unsigned short* lA, unsigned short* lB,
                                          f32x4 acc[4][2])
{
    const int tid = threadIdx.x, lane = tid & 63, wid = tid >> 6;
    const int wr = wid >> 1, wc = wid & 1;
    #pragma unroll
    for (int mi = 0; mi < 4; mi++)
        #pragma unroll
        for (int ni = 0; ni < 2; ni++) acc[mi][ni] = (f32x4){0.f, 0.f, 0.f, 0.f};

    for (int kt = 0; kt < KTOT; kt += 192) {
        __syncthreads();
        #pragma unroll
        for (int c = tid; c < 128 * 24; c += 256) {     // A: 128 rows x 24 16B-chunks
            int row = c / 24, k16 = c - row * 24;
            bf16x8 v = *(const bf16x8*)(A + (long)(m0 + row) * lda + kt + k16 * 8);
            *(bf16x8*)((char*)lA + row * 384 + ((k16 * 16) ^ ((row & 7) << 4))) = v;
        }
        #pragma unroll
        for (int c = tid; c < 64 * 24; c += 256) {      // B: 64 rows x 24 chunks
            int row = c / 24, k16 = c - row * 24;
            bf16x8 v = *(const bf16x8*)(Bt + (long)(n0 + row) * ldb + kt + k16 * 8);
            *(bf16x8*)((char*)lB + row * 384 + ((k16 * 16) ^ ((row & 7) << 4))) = v;
        }
        __syncthreads();
        #pragma unroll
        for (int ks = 0; ks < 6; ks++) {                // 192 / 32
            int kb = ks * 64 + ((lane >> 4) << 4);      // byte offset of this lane-group's 8 k-elems
            bf16x8 bfr[2];
            #pragma unroll
            for (int ni = 0; ni < 2; ni++) {
                int row = wc * 32 + ni * 16 + (lane & 15);
                bfr[ni] = *(const bf16x8*)((char*)lB + row * 384 + (kb ^ ((row & 7) << 4)));
            }
            #pragma unroll
            for (int mi = 0; mi < 4; mi++) {
                int row = wr * 64 + mi * 16 + (lane & 15);
                bf16x8 afr = *(const bf16x8*)((char*)lA + row * 384 + (kb ^ ((row & 7) << 4)));
                #pragma unroll
                for (int ni = 0; ni < 2; ni++)
                    acc[mi][ni] = __builtin_amdgcn_mfma_f32_16x16x32_bf16(afr, bfr[ni], acc[mi][ni], 0, 0, 0);
            }
        }
    }
}

// ---------------- QKV GEMM: win @ qkv_wt + b -> q/k/v chunks of d_out (f32) ----------------
__global__ __launch_bounds__(256) void k_gemm_qkv(const unsigned short* __restrict__ A,
                                                  const unsigned short* __restrict__ Bt,
                                                  const float* __restrict__ bias,
                                                  float* __restrict__ outq)
{
    __shared__ unsigned short lA[128 * 192];
    __shared__ unsigned short lB[64 * 192];
    f32x4 acc[4][2];
    int m0 = blockIdx.y * 128, n0 = blockIdx.x * 64;
    gemm_tile<192>(A, 192, Bt, 192, m0, n0, lA, lB, acc);
    int lane = threadIdx.x & 63, wid = threadIdx.x >> 6;
    int wr = wid >> 1, wc = wid & 1;
    #pragma unroll
    for (int mi = 0; mi < 4; mi++)
        #pragma unroll
        for (int ni = 0; ni < 2; ni++) {
            int gcol = n0 + wc * 32 + ni * 16 + (lane & 15);
            int ch = gcol / 192; int cc = gcol - ch * 192;
            float bv = bias[gcol];
            float* base = outq + (long)ch * OUTCH + cc;
            #pragma unroll
            for (int r = 0; r < 4; r++) {
                long grow = m0 + wr * 64 + mi * 16 + ((lane >> 4) << 2) + r;
                base[grow * 192] = acc[mi][ni][r] + bv;
            }
        }
}

// ---------------- proj GEMM + window reverse + roll(+3,+3) + residual -> xo f32 (d_out ch0) ---------
__global__ __launch_bounds__(256) void k_gemm_proj(const unsigned short* __restrict__ A,
                                                   const unsigned short* __restrict__ Bt,
                                                   const float* __restrict__ bias,
                                                   const float* __restrict__ x,
                                                   float* __restrict__ xo)
{
    __shared__ unsigned short lA[128 * 192];
    __shared__ unsigned short lB[64 * 192];
    f32x4 acc[4][2];
    int m0 = blockIdx.y * 128, n0 = blockIdx.x * 64;
    gemm_tile<192>(A, 192, Bt, 192, m0, n0, lA, lB, acc);
    int lane = threadIdx.x & 63, wid = threadIdx.x >> 6;
    int wr = wid >> 1, wc = wid & 1;
    #pragma unroll
    for (int mi = 0; mi < 4; mi++)
        #pragma unroll
        for (int ni = 0; ni < 2; ni++) {
            int gcol = n0 + wc * 32 + ni * 16 + (lane & 15);
            float bv = bias[gcol];
            #pragma unroll
            for (int r = 0; r < 4; r++) {
                int t = m0 + wr * 64 + mi * 16 + ((lane >> 4) << 2) + r;   // window token
                int w = t / 49, n = t - w * 49;
                int bb = w >> 6, widx = w & 63;
                int wi = widx >> 3, wj = widx & 7;
                int rr = n / 7, ss = n - rr * 7;
                int ho = wi * 7 + rr + 3; if (ho >= 56) ho -= 56;          // roll(+SHIFT)
                int wo = wj * 7 + ss + 3; if (wo >= 56) wo -= 56;
                long tp = ((long)(bb * 56 + ho) * 56 + wo);
                xo[tp * 192 + gcol] = x[tp * 192 + gcol] + acc[mi][ni][r] + bv;
            }
        }
}

// ---------------- FC1 + exact GELU -> G (bf16 ws chunk) ----------------
__global__ __launch_bounds__(256) void k_gemm_fc1(const unsigned short* __restrict__ A,
                                                  const unsigned short* __restrict__ Bt,
                                                  const float* __restrict__ bias,
                                                  unsigned short* __restrict__ G)
{
    __shared__ unsigned short lA[128 * 192];
    __shared__ unsigned short lB[64 * 192];
    f32x4 acc[4][2];
    int m0 = blockIdx.y * 128, n0 = blockIdx.x * 64;
    gemm_tile<192>(A, 192, Bt, 192, m0, n0, lA, lB, acc);
    int lane = threadIdx.x & 63, wid = threadIdx.x >> 6;
    int wr = wid >> 1, wc = wid & 1;
    #pragma unroll
    for (int mi = 0; mi < 4; mi++)
        #pragma unroll
        for (int ni = 0; ni < 2; ni++) {
            int gcol = n0 + wc * 32 + ni * 16 + (lane & 15);
            float bv = bias[gcol];
            #pragma unroll
            for (int r = 0; r < 4; r++) {
                long grow = m0 + wr * 64 + mi * 16 + ((lane >> 4) << 2) + r;
                float v = acc[mi][ni][r] + bv;
                float ge = 0.5f * v * (1.f + erff(v * 0.70710678118654752f));
                G[grow * 768 + gcol] = f2bf(ge);
            }
        }
}

// ---------------- FC2 + residual (in-place on f32 xo chunk of d_out) ----------------
__global__ __launch_bounds__(256) void k_gemm_fc2(const unsigned short* __restrict__ A,
                                                  const unsigned short* __restrict__ Bt,
                                                  const float* __restrict__ bias,
                                                  float* __restrict__ xo)
{
    __shared__ unsigned short lA[128 * 192];
    __shared__ unsigned short lB[64 * 192];
    f32x4 acc[4][2];
    int m0 = blockIdx.y * 128, n0 = blockIdx.x * 64;
    gemm_tile<768>(A, 768, Bt, 768, m0, n0, lA, lB, acc);
    int lane = threadIdx.x & 63, wid = threadIdx.x >> 6;
    int wr = wid >> 1, wc = wid & 1;
    #pragma unroll
    for (int mi = 0; mi < 4; mi++)
        #pragma unroll
        for (int ni = 0; ni < 2; ni++) {
            int gcol = n0 + wc * 32 + ni * 16 + (lane & 15);
            float bv = bias[gcol];
            #pragma unroll
            for (int r = 0; r < 4; r++) {
                long grow = m0 + wr * 64 + mi * 16 + ((lane >> 4) << 2) + r;
                xo[grow * 192 + gcol] += acc[mi][ni][r] + bv;
            }
        }
}

// ---------------- attention v2: one block (6 waves = 6 heads) per window ----------------
// LDS = ATT only: [6][49][67] f32 = 78,792 B  -> 2 blocks/CU (~37% occupancy).
// K/V/Q fragments load directly from global f32 (zero reuse per element -> staging was waste).
// V-fragments prefetched at kernel start (latency hidden under QK^T + mixes + softmax).
// Softmax: row-per-lane (294 rows across 384 lanes, one pass, no cross-lane ops).
#define ATS 67
__global__ __launch_bounds__(384) void k_attn(const float* __restrict__ qg,
                                              const float* __restrict__ kg,
                                              const float* __restrict__ vg,
                                              const float* __restrict__ rpb,
                                              const float* __restrict__ plw,
                                              const float* __restrict__ plb,
                                              const float* __restrict__ pww,
                                              const float* __restrict__ pwb,
                                              unsigned short* __restrict__ aout)
{
    __shared__ float ATT[6][49][ATS];          // scores; cols [49,64) zeroed for padded-K PV

    int w = blockIdx.x, widx = w & 63;
    int tid = threadIdx.x, lane = tid & 63, h = tid >> 6;   // wave id == head
    const long base = (long)w * 49 * 192;

    // ---- prefetch V fragments (B-operand of PV): vfr[kst][ni], n clamped to 48 (pad cols of P are 0)
    bf16x8 vfr[2][2];
    #pragma unroll
    for (int kst = 0; kst < 2; kst++)
        #pragma unroll
        for (int ni = 0; ni < 2; ni++) {
            int d = ni * 16 + (lane & 15);
            #pragma unroll
            for (int j = 0; j < 8; j++) {
                int n = kst * 32 + ((lane >> 4) << 3) + j; if (n > 48) n = 48;
                vfr[kst][ni][j] = (short)f2bf(vg[base + n * 192 + h * 32 + d]);
            }
        }

    // ---- zero ATT pad cols [49,64) (must complete before PV; several syncs intervene) ----
    for (int c = tid; c < 6 * 49 * 15; c += 384) {
        int g2 = c / (49 * 15), rem = c - g2 * (49 * 15);
        int m = rem / 15, n = 49 + (rem - m * 15);
        ATT[g2][m][n] = 0.f;
    }

    // ---- QK^T (per head), fragments straight from global ----
    bf16x8 qfr[4], kfr[4];
    #pragma unroll
    for (int mi = 0; mi < 4; mi++) {
        int m = mi * 16 + (lane & 15); if (m > 48) m = 48;
        const float* qp = qg + base + m * 192 + h * 32 + ((lane >> 4) << 3);
        #pragma unroll
        for (int j = 0; j < 8; j++) qfr[mi][j] = (short)f2bf(qp[j]);
    }
    #pragma unroll
    for (int ni = 0; ni < 4; ni++) {
        int n = ni * 16 + (lane & 15); if (n > 48) n = 48;
        const float* kp = kg + base + n * 192 + h * 32 + ((lane >> 4) << 3);
        #pragma unroll
        for (int j = 0; j < 8; j++) kfr[ni][j] = (short)f2bf(kp[j]);
    }
    f32x4 sa[4][4];
    #pragma unroll
    for (int ni = 0; ni < 4; ni++)
        #pragma unroll
        for (int mi = 0; mi < 4; mi++)
            sa[mi][ni] = __builtin_amdgcn_mfma_f32_16x16x32_bf16(qfr[mi], kfr[ni], (f32x4){0.f, 0.f, 0.f, 0.f}, 0, 0, 0);
    const float scale = 0.17677669529663687f;   // 32^-0.5
    #pragma unroll
    for (int mi = 0; mi < 4; mi++)
        #pragma unroll
        for (int ni = 0; ni < 4; ni++)
            #pragma unroll
            for (int r = 0; r < 4; r++) {
                int m = mi * 16 + ((lane >> 4) << 2) + r, n = ni * 16 + (lane & 15);
                if (m < 49 && n < 49) {
                    int rq = m / 7, cq = m - rq * 7, rk = n / 7, ck = n - rk * 7;
                    int ridx = (rq - rk + 6) * 13 + (cq - ck + 6);
                    ATT[h][m][n] = sa[mi][ni][r] * scale + rpb[ridx * 6 + h];
                }
            }
    __syncthreads();

    // ---- pl head-mix + shift mask (in place) ----
    int wi = widx >> 3, wj = widx & 7;
    for (int p = tid; p < 2401; p += 384) {
        int m = p / 49, n = p - m * 49;
        float a[6];
        #pragma unroll
        for (int g2 = 0; g2 < 6; g2++) a[g2] = ATT[g2][m][n];
        int rq = m / 7, cq = m - rq * 7, rk = n / 7, ck = n - rk * 7;
        int ghq = wi * 7 + rq, gwq = wj * 7 + cq, ghk = wi * 7 + rk, gwk = wj * 7 + ck;
        int regq = (ghq < 49 ? 0 : (ghq < 53 ? 1 : 2)) * 3 + (gwq < 49 ? 0 : (gwq < 53 ? 1 : 2));
        int regk = (ghk < 49 ? 0 : (ghk < 53 ? 1 : 2)) * 3 + (gwk < 49 ? 0 : (gwk < 53 ? 1 : 2));
        float msk = (regq != regk) ? -100.f : 0.f;
        #pragma unroll
        for (int g2 = 0; g2 < 6; g2++) {
            float v = plb[g2] + msk;
            #pragma unroll
            for (int h2 = 0; h2 < 6; h2++) v += a[h2] * plw[h2 * 6 + g2];
            ATT[g2][m][n] = v;
        }
    }
    __syncthreads();

    // ---- softmax: row-per-lane, one pass ----
    if (tid < 294) {
        int g2 = tid / 49, m = tid - g2 * 49;
        float* row = &ATT[g2][m][0];
        float mx = row[0];
        #pragma unroll
        for (int j = 1; j < 49; j++) mx = fmaxf(mx, row[j]);
        float e[49]; float sm = 0.f;
        #pragma unroll
        for (int j = 0; j < 49; j++) { e[j] = __expf(row[j] - mx); sm += e[j]; }
        float inv = 1.f / sm;
        #pragma unroll
        for (int j = 0; j < 49; j++) row[j] = e[j] * inv;
    }
    __syncthreads();

    // ---- pw head-mix (in place) ----
    for (int p = tid; p < 2401; p += 384) {
        int m = p / 49, n = p - m * 49;
        float a[6];
        #pragma unroll
        for (int g2 = 0; g2 < 6; g2++) a[g2] = ATT[g2][m][n];
        #pragma unroll
        for (int g2 = 0; g2 < 6; g2++) {
            float v = pwb[g2];
            #pragma unroll
            for (int h2 = 0; h2 < 6; h2++) v += a[h2] * pww[h2 * 6 + g2];
            ATT[g2][m][n] = v;
        }
    }
    __syncthreads();

    // ---- PV (per head): out[m][d] = sum_n P'[m][n] * V[n][d] ----
    f32x4 oa[4][2];
    #pragma unroll
    for (int mi = 0; mi < 4; mi++)
        #pragma unroll
        for (int ni = 0; ni < 2; ni++) oa[mi][ni] = (f32x4){0.f, 0.f, 0.f, 0.f};
    #pragma unroll
    for (int kst = 0; kst < 2; kst++) {
        #pragma unroll
        for (int mi = 0; mi < 4; mi++) {
            int m = mi * 16 + (lane & 15); if (m > 48) m = 48;
            const float* ap = &ATT[h][m][kst * 32 + ((lane >> 4) << 3)];
            bf16x8 afr;
            #pragma unroll
            for (int j = 0; j < 8; j++) afr[j] = (short)f2bf(ap[j]);
            #pragma unroll
            for (int ni = 0; ni < 2; ni++)
                oa[mi][ni] = __builtin_amdgcn_mfma_f32_16x16x32_bf16(afr, vfr[kst][ni], oa[mi][ni], 0, 0, 0);
        }
    }
    #pragma unroll
    for (int mi = 0; mi < 4; mi++)
        #pragma unroll
        for (int ni = 0; ni < 2; ni++)
            #pragma unroll
            for (int r = 0; r < 4; r++) {
                int m = mi * 16 + ((lane >> 4) << 2) + r, d = ni * 16 + (lane & 15);
                if (m < 49) aout[base + m * 192 + h * 32 + d] = f2bf(oa[mi][ni][r]);
            }
}

// ---------------- launcher ----------------
extern "C" void kernel_launch(void* const* d_in, const int* in_sizes, int n_in,
                              void* d_out, int out_size, void* d_ws, size_t ws_size,
                              hipStream_t stream)
{
    const float* x      = (const float*)d_in[0];
    const float* n1g    = (const float*)d_in[1];
    const float* n1b    = (const float*)d_in[2];
    const float* qkv_w  = (const float*)d_in[3];
    const float* qkv_b  = (const float*)d_in[4];
    const float* proj_w = (const float*)d_in[5];
    const float* proj_b = (const float*)d_in[6];
    const float* rpb    = (const float*)d_in[7];
    const float* pl_w   = (const float*)d_in[8];
    const float* pl_b   = (const float*)d_in[9];
    const float* pw_w   = (const float*)d_in[10];
    const float* pw_b   = (const float*)d_in[11];
    const float* n2g    = (const float*)d_in[12];
    const float* n2b    = (const float*)d_in[13];
    const float* fc1_w  = (const float*)d_in[14];
    const float* fc1_b  = (const float*)d_in[15];
    const float* fc2_w  = (const float*)d_in[16];
    const float* fc2_b  = (const float*)d_in[17];

    float* out   = (float*)d_out;   // f32: [xo | q | k | v], each OUTCH elements
    float* out_q = out + OUTCH;
    float* out_k = out + 2 * OUTCH;
    float* out_v = out + 3 * OUTCH;

    // ws: bufT 38,535,168 (bf16 TOKx192, time-shared win/attn-out/h2)
    //     bufG 19,267,584 (bf16 MLPRx768) | bufW 884,736  => total 58,687,488 B
    char* ws = (char*)d_ws;
    unsigned short* bufT = (unsigned short*)ws;
    unsigned short* bufG = (unsigned short*)(ws + 38535168);
    unsigned short* bufW = (unsigned short*)(ws + 57802752);

    k_prep_w<<<1728, 256, 0, stream>>>(qkv_w, proj_w, fc1_w, fc2_w, bufW);
    k_ln1<<<25088, 256, 0, stream>>>(x, n1g, n1b, bufT);                      // bufT = win
    k_gemm_qkv<<<dim3(9, 784), 256, 0, stream>>>(bufT, bufW, qkv_b, out_q);   // q/k/v f32
    k_attn<<<NWIN, 384, 0, stream>>>(out_q, out_k, out_v,
                                     rpb, pl_w, pl_b, pw_w, pw_b, bufT);      // bufT = attn out
    k_gemm_proj<<<dim3(3, 784), 256, 0, stream>>>(bufT, bufW + 110592, proj_b, x, out); // out[0:OUTCH] = pre-MLP xo
    k_ln2<<<25088, 256, 0, stream>>>(out, n2g, n2b, bufT);                    // bufT = h2
    for (int c = 0; c < 8; c++) {
        long off = (long)c * MLPR * 192;
        k_gemm_fc1<<<dim3(12, 98), 256, 0, stream>>>(bufT + off, bufW + 147456, fc1_b, bufG);
        k_gemm_fc2<<<dim3(3, 98), 256, 0, stream>>>(bufG, bufW + 294912, fc2_b, out + off);
    }
}

// Round 6
// 539.466 us; speedup vs baseline: 1.8232x; 1.4445x over previous
//
#include <hip/hip_runtime.h>
#include <math.h>

// ---------------- problem constants ----------------
#define TOK   100352            // B * H * W  = 32*56*56  (= B_ * N = 2048*49)
#define OUTCH 19267584L         // TOK * 192, elements per output chunk (f32)
#define NWIN  2048

typedef __attribute__((ext_vector_type(4))) float f32x4;
typedef __attribute__((ext_vector_type(8))) short bf16x8;

__device__ __forceinline__ unsigned short f2bf(float f) {
    unsigned u = __builtin_bit_cast(unsigned, f);
    u += 0x7FFFu + ((u >> 16) & 1u);          // round-to-nearest-even
    return (unsigned short)(u >> 16);
}
__device__ __forceinline__ float bf2f(unsigned short s) {
    return __builtin_bit_cast(float, (unsigned)s << 16);
}

// ---------------- weight prep: transpose + bf16 cast ----------------
// layout in wt (bf16):
//  [0,110592)        qkv_wt [576][192]
//  [110592,147456)   proj_wt[192][192]
//  [147456,294912)   fc1_wt [768][192]
//  [294912,442368)   fc2_wt [192][768]
__global__ __launch_bounds__(256) void k_prep_w(const float* __restrict__ qkv_w,
                                                const float* __restrict__ proj_w,
                                                const float* __restrict__ fc1_w,
                                                const float* __restrict__ fc2_w,
                                                unsigned short* __restrict__ wt)
{
    int i = blockIdx.x * 256 + threadIdx.x;   // grid covers exactly 442368
    float v;
    if (i < 110592)       { int n = i / 192, k = i - n * 192;            v = qkv_w[k * 576 + n]; }
    else if (i < 147456)  { int j = i - 110592; int n = j / 192, k = j - n * 192; v = proj_w[k * 192 + n]; }
    else if (i < 294912)  { int j = i - 147456; int n = j / 192, k = j - n * 192; v = fc1_w[k * 768 + n]; }
    else                  { int j = i - 294912; int n = j / 768, k = j - n * 768; v = fc2_w[k * 192 + n]; }
    wt[i] = f2bf(v);
}

// ---------------- LN1 + roll(-3,-3) + window partition -> bf16 win ----------------
__global__ __launch_bounds__(256) void k_ln1(const float* __restrict__ x,
                                             const float* __restrict__ g,
                                             const float* __restrict__ b,
                                             unsigned short* __restrict__ win)
{
    int lane = threadIdx.x & 63;
    int t = blockIdx.x * 4 + (threadIdx.x >> 6);      // window-token index
    int w = t / 49, n = t - w * 49;
    int bb = w >> 6, widx = w & 63;
    int wi = widx >> 3, wj = widx & 7;
    int r = n / 7, s = n - r * 7;
    int hh = wi * 7 + r + 3; if (hh >= 56) hh -= 56;  // roll(-SHIFT): rolled(h)=orig(h+3)
    int ww = wj * 7 + s + 3; if (ww >= 56) ww -= 56;
    const float* src = x + ((long)(bb * 56 + hh) * 56 + ww) * 192;
    float v0 = src[lane], v1 = src[lane + 64], v2 = src[lane + 128];
    float sum = v0 + v1 + v2;
    float sq  = v0 * v0 + v1 * v1 + v2 * v2;
    #pragma unroll
    for (int o = 32; o; o >>= 1) { sum += __shfl_xor(sum, o); sq += __shfl_xor(sq, o); }
    float mu = sum * (1.f / 192.f);
    float rs = rsqrtf(sq * (1.f / 192.f) - mu * mu + 1e-5f);
    unsigned short* dst = win + (long)t * 192;
    dst[lane]       = f2bf((v0 - mu) * rs * g[lane]       + b[lane]);
    dst[lane + 64]  = f2bf((v1 - mu) * rs * g[lane + 64]  + b[lane + 64]);
    dst[lane + 128] = f2bf((v2 - mu) * rs * g[lane + 128] + b[lane + 128]);
}

// ---------------- LN2: f32 xo -> bf16 h2 ----------------
__global__ __launch_bounds__(256) void k_ln2(const float* __restrict__ xo,
                                             const float* __restrict__ g,
                                             const float* __restrict__ b,
                                             unsigned short* __restrict__ h2)
{
    int lane = threadIdx.x & 63;
    long t = (long)blockIdx.x * 4 + (threadIdx.x >> 6);
    const float* src = xo + t * 192;
    float v0 = src[lane], v1 = src[lane + 64], v2 = src[lane + 128];
    float sum = v0 + v1 + v2;
    float sq  = v0 * v0 + v1 * v1 + v2 * v2;
    #pragma unroll
    for (int o = 32; o; o >>= 1) { sum += __shfl_xor(sum, o); sq += __shfl_xor(sq, o); }
    float mu = sum * (1.f / 192.f);
    float rs = rsqrtf(sq * (1.f / 192.f) - mu * mu + 1e-5f);
    unsigned short* dst = h2 + t * 192;
    dst[lane]       = f2bf((v0 - mu) * rs * g[lane]       + b[lane]);
    dst[lane + 64]  = f2bf((v1 - mu) * rs * g[lane + 64]  + b[lane + 64]);
    dst[lane + 128] = f2bf((v2 - mu) * rs * g[lane + 128] + b[lane + 128]);
}

// ---------------- shared GEMM main loop (qkv / proj) ----------------
// BM=128, BN=64, staged BK=192. A: [M][lda] bf16 row-major. Bt: [N][ldb] bf16 (transposed weights).
// LDS tiles XOR-swizzled (byte ^= (row&7)<<4) to keep ds_read_b128 conflict-free at 384 B row stride.
template<int KTOT>
__device__ __forceinline__ void gemm_tile(const unsigned short* __restrict__ A, int lda,
                                          const unsigned short* __restrict__ Bt, int ldb,
                                          int m0, int n0,
                                          unsigned short* lA, unsigned short* lB,
                                          f32x4 acc[4][2])
{
    const int tid = threadIdx.x, lane = tid & 63, wid = tid >> 6;
    const int wr = wid >> 1, wc = wid & 1;
    #pragma unroll
    for (int mi = 0; mi < 4; mi++)
        #pragma unroll
        for (int ni = 0; ni < 2; ni++) acc[mi][ni] = (f32x4){0.f, 0.f, 0.f, 0.f};

    for (int kt = 0; kt < KTOT; kt += 192) {
        __syncthreads();
        #pragma unroll
        for (int c = tid; c < 128 * 24; c += 256) {     // A: 128 rows x 24 16B-chunks
            int row = c / 24, k16 = c - row * 24;
            bf16x8 v = *(const bf16x8*)(A + (long)(m0 + row) * lda + kt + k16 * 8);
            *(bf16x8*)((char*)lA + row * 384 + ((k16 * 16) ^ ((row & 7) << 4))) = v;
        }
        #pragma unroll
        for (int c = tid; c < 64 * 24; c += 256) {      // B: 64 rows x 24 chunks
            int row = c / 24, k16 = c - row * 24;
            bf16x8 v = *(const bf16x8*)(Bt + (long)(n0 + row) * ldb + kt + k16 * 8);
            *(bf16x8*)((char*)lB + row * 384 + ((k16 * 16) ^ ((row & 7) << 4))) = v;
        }
        __syncthreads();
        #pragma unroll
        for (int ks = 0; ks < 6; ks++) {                // 192 / 32
            int kb = ks * 64 + ((lane >> 4) << 4);      // byte offset of this lane-group's 8 k-elems
            bf16x8 bfr[2];
            #pragma unroll
            for (int ni = 0; ni < 2; ni++) {
                int row = wc * 32 + ni * 16 + (lane & 15);
                bfr[ni] = *(const bf16x8*)((char*)lB + row * 384 + (kb ^ ((row & 7) << 4)));
            }
            #pragma unroll
            for (int mi = 0; mi < 4; mi++) {
                int row = wr * 64 + mi * 16 + (lane & 15);
                bf16x8 afr = *(const bf16x8*)((char*)lA + row * 384 + (kb ^ ((row & 7) << 4)));
                #pragma unroll
                for (int ni = 0; ni < 2; ni++)
                    acc[mi][ni] = __builtin_amdgcn_mfma_f32_16x16x32_bf16(afr, bfr[ni], acc[mi][ni], 0, 0, 0);
            }
        }
    }
}

// ---------------- QKV GEMM: win @ qkv_wt + b -> q/k/v chunks of d_out (f32) ----------------
__global__ __launch_bounds__(256) void k_gemm_qkv(const unsigned short* __restrict__ A,
                                                  const unsigned short* __restrict__ Bt,
                                                  const float* __restrict__ bias,
                                                  float* __restrict__ outq)
{
    __shared__ unsigned short lA[128 * 192];
    __shared__ unsigned short lB[64 * 192];
    f32x4 acc[4][2];
    int m0 = blockIdx.y * 128, n0 = blockIdx.x * 64;
    gemm_tile<192>(A, 192, Bt, 192, m0, n0, lA, lB, acc);
    int lane = threadIdx.x & 63, wid = threadIdx.x >> 6;
    int wr = wid >> 1, wc = wid & 1;
    #pragma unroll
    for (int mi = 0; mi < 4; mi++)
        #pragma unroll
        for (int ni = 0; ni < 2; ni++) {
            int gcol = n0 + wc * 32 + ni * 16 + (lane & 15);
            int ch = gcol / 192; int cc = gcol - ch * 192;
            float bv = bias[gcol];
            float* base = outq + (long)ch * OUTCH + cc;
            #pragma unroll
            for (int r = 0; r < 4; r++) {
                long grow = m0 + wr * 64 + mi * 16 + ((lane >> 4) << 2) + r;
                base[grow * 192] = acc[mi][ni][r] + bv;
            }
        }
}

// ---------------- proj GEMM + window reverse + roll(+3,+3) + residual -> xo f32 (d_out ch0) ---------
__global__ __launch_bounds__(256) void k_gemm_proj(const unsigned short* __restrict__ A,
                                                   const unsigned short* __restrict__ Bt,
                                                   const float* __restrict__ bias,
                                                   const float* __restrict__ x,
                                                   float* __restrict__ xo)
{
    __shared__ unsigned short lA[128 * 192];
    __shared__ unsigned short lB[64 * 192];
    f32x4 acc[4][2];
    int m0 = blockIdx.y * 128, n0 = blockIdx.x * 64;
    gemm_tile<192>(A, 192, Bt, 192, m0, n0, lA, lB, acc);
    int lane = threadIdx.x & 63, wid = threadIdx.x >> 6;
    int wr = wid >> 1, wc = wid & 1;
    #pragma unroll
    for (int mi = 0; mi < 4; mi++)
        #pragma unroll
        for (int ni = 0; ni < 2; ni++) {
            int gcol = n0 + wc * 32 + ni * 16 + (lane & 15);
            float bv = bias[gcol];
            #pragma unroll
            for (int r = 0; r < 4; r++) {
                int t = m0 + wr * 64 + mi * 16 + ((lane >> 4) << 2) + r;   // window token
                int w = t / 49, n = t - w * 49;
                int bb = w >> 6, widx = w & 63;
                int wi = widx >> 3, wj = widx & 7;
                int rr = n / 7, ss = n - rr * 7;
                int ho = wi * 7 + rr + 3; if (ho >= 56) ho -= 56;          // roll(+SHIFT)
                int wo = wj * 7 + ss + 3; if (wo >= 56) wo -= 56;
                long tp = ((long)(bb * 56 + ho) * 56 + wo);
                xo[tp * 192 + gcol] = x[tp * 192 + gcol] + acc[mi][ni][r] + bv;
            }
        }
}

// ---------------- fused MLP: xo += fc2(gelu(fc1(h2))) , BM=64, 4 slabs of 192 ----------------
// LDS 49,152 B -> 3 blocks/CU. W1/W2 B-fragments read from global (L2-resident, 590 KB total).
__global__ __launch_bounds__(256) void k_mlp(const unsigned short* __restrict__ h2,
                                             const unsigned short* __restrict__ w1t,  // [768][192]
                                             const float* __restrict__ b1,
                                             const unsigned short* __restrict__ w2t,  // [192][768]
                                             const float* __restrict__ b2,
                                             float* __restrict__ xo)
{
    __shared__ unsigned short lA[64 * 192];   // h2 tile, swizzled
    __shared__ unsigned short lH[64 * 192];   // gelu(fc1) slab, swizzled
    const int tid = threadIdx.x, lane = tid & 63, wv = tid >> 6;
    const long m0 = (long)blockIdx.x * 64;

    // stage A (64 rows x 24 chunks)
    #pragma unroll
    for (int c = tid; c < 64 * 24; c += 256) {
        int row = c / 24, k16 = c - row * 24;
        bf16x8 v = *(const bf16x8*)(h2 + (m0 + row) * 192 + k16 * 8);
        *(bf16x8*)((char*)lA + row * 384 + ((k16 * 16) ^ ((row & 7) << 4))) = v;
    }

    f32x4 acc2[4][3];
    #pragma unroll
    for (int mi = 0; mi < 4; mi++)
        #pragma unroll
        for (int ni = 0; ni < 3; ni++) acc2[mi][ni] = (f32x4){0.f, 0.f, 0.f, 0.f};
    __syncthreads();

    for (int s = 0; s < 4; s++) {
        // GEMM1: acc1 = A-tile @ W1t[slab]; wave wv owns slab cols [wv*48, wv*48+48)
        f32x4 acc1[4][3];
        #pragma unroll
        for (int mi = 0; mi < 4; mi++)
            #pragma unroll
            for (int ni = 0; ni < 3; ni++) acc1[mi][ni] = (f32x4){0.f, 0.f, 0.f, 0.f};
        #pragma unroll
        for (int ks = 0; ks < 6; ks++) {
            int kb = ks * 64 + ((lane >> 4) << 4);
            bf16x8 bfr[3];
            #pragma unroll
            for (int ni = 0; ni < 3; ni++) {
                int n = s * 192 + wv * 48 + ni * 16 + (lane & 15);
                bfr[ni] = *(const bf16x8*)(w1t + (long)n * 192 + ks * 32 + ((lane >> 4) << 3));
            }
            #pragma unroll
            for (int mi = 0; mi < 4; mi++) {
                int row = mi * 16 + (lane & 15);
                bf16x8 afr = *(const bf16x8*)((char*)lA + row * 384 + (kb ^ ((row & 7) << 4)));
                #pragma unroll
                for (int ni = 0; ni < 3; ni++)
                    acc1[mi][ni] = __builtin_amdgcn_mfma_f32_16x16x32_bf16(afr, bfr[ni], acc1[mi][ni], 0, 0, 0);
            }
        }
        __syncthreads();     // previous slab's GEMM2 reads of lH are done
        // GELU -> lH (swizzled scalar bf16 stores; XOR touches byte bits 4..6 only)
        #pragma unroll
        for (int mi = 0; mi < 4; mi++)
            #pragma unroll
            for (int ni = 0; ni < 3; ni++) {
                int col = wv * 48 + ni * 16 + (lane & 15);
                float bv = b1[s * 192 + col];
                #pragma unroll
                for (int r = 0; r < 4; r++) {
                    int row = mi * 16 + ((lane >> 4) << 2) + r;
                    float v = acc1[mi][ni][r] + bv;
                    float ge = 0.5f * v * (1.f + erff(v * 0.70710678118654752f));
                    *(unsigned short*)((char*)lH + row * 384 + ((2 * col) ^ ((row & 7) << 4))) = f2bf(ge);
                }
            }
        __syncthreads();
        // GEMM2 partial: acc2 += H_slab @ W2t[:, slab]; wave wv owns out cols [wv*48, wv*48+48)
        #pragma unroll
        for (int ks = 0; ks < 6; ks++) {
            int kb = ks * 64 + ((lane >> 4) << 4);
            bf16x8 bfr[3];
            #pragma unroll
            for (int ni = 0; ni < 3; ni++) {
                int n = wv * 48 + ni * 16 + (lane & 15);
                bfr[ni] = *(const bf16x8*)(w2t + (long)n * 768 + s * 192 + ks * 32 + ((lane >> 4) << 3));
            }
            #pragma unroll
            for (int mi = 0; mi < 4; mi++) {
                int row = mi * 16 + (lane & 15);
                bf16x8 afr = *(const bf16x8*)((char*)lH + row * 384 + (kb ^ ((row & 7) << 4)));
                #pragma unroll
                for (int ni = 0; ni < 3; ni++)
                    acc2[mi][ni] = __builtin_amdgcn_mfma_f32_16x16x32_bf16(afr, bfr[ni], acc2[mi][ni], 0, 0, 0);
            }
        }
    }
    // epilogue: xo += acc2 + b2 (in place, each element touched exactly once)
    #pragma unroll
    for (int mi = 0; mi < 4; mi++)
        #pragma unroll
        for (int ni = 0; ni < 3; ni++) {
            int gcol = wv * 48 + ni * 16 + (lane & 15);
            float bv = b2[gcol];
            #pragma unroll
            for (int r = 0; r < 4; r++) {
                long grow = m0 + mi * 16 + ((lane >> 4) << 2) + r;
                xo[grow * 192 + gcol] += acc2[mi][ni][r] + bv;
            }
        }
}

// ---------------- attention v2: one block (6 waves = 6 heads) per window ----------------
// LDS = ATT only: [6][49][67] f32 = 78,792 B  -> 2 blocks/CU.
// K/V/Q fragments load directly from global f32; V prefetched at kernel start.
#define ATS 67
__global__ __launch_bounds__(384) void k_attn(const float* __restrict__ qg,
                                              const float* __restrict__ kg,
                                              const float* __restrict__ vg,
                                              const float* __restrict__ rpb,
                                              const float* __restrict__ plw,
                                              const float* __restrict__ plb,
                                              const float* __restrict__ pww,
                                              const float* __restrict__ pwb,
                                              unsigned short* __restrict__ aout)
{
    __shared__ float ATT[6][49][ATS];          // scores; cols [49,64) zeroed for padded-K PV

    int w = blockIdx.x, widx = w & 63;
    int tid = threadIdx.x, lane = tid & 63, h = tid >> 6;   // wave id == head
    const long base = (long)w * 49 * 192;

    // ---- prefetch V fragments (B-operand of PV): n clamped to 48 (pad cols of P are 0)
    bf16x8 vfr[2][2];
    #pragma unroll
    for (int kst = 0; kst < 2; kst++)
        #pragma unroll
        for (int ni = 0; ni < 2; ni++) {
            int d = ni * 16 + (lane & 15);
            #pragma unroll
            for (int j = 0; j < 8; j++) {
                int n = kst * 32 + ((lane >> 4) << 3) + j; if (n > 48) n = 48;
                vfr[kst][ni][j] = (short)f2bf(vg[base + n * 192 + h * 32 + d]);
            }
        }

    // ---- zero ATT pad cols [49,64) ----
    for (int c = tid; c < 6 * 49 * 15; c += 384) {
        int g2 = c / (49 * 15), rem = c - g2 * (49 * 15);
        int m = rem / 15, n = 49 + (rem - m * 15);
        ATT[g2][m][n] = 0.f;
    }

    // ---- QK^T (per head), fragments straight from global ----
    bf16x8 qfr[4], kfr[4];
    #pragma unroll
    for (int mi = 0; mi < 4; mi++) {
        int m = mi * 16 + (lane & 15); if (m > 48) m = 48;
        const float* qp = qg + base + m * 192 + h * 32 + ((lane >> 4) << 3);
        #pragma unroll
        for (int j = 0; j < 8; j++) qfr[mi][j] = (short)f2bf(qp[j]);
    }
    #pragma unroll
    for (int ni = 0; ni < 4; ni++) {
        int n = ni * 16 + (lane & 15); if (n > 48) n = 48;
        const float* kp = kg + base + n * 192 + h * 32 + ((lane >> 4) << 3);
        #pragma unroll
        for (int j = 0; j < 8; j++) kfr[ni][j] = (short)f2bf(kp[j]);
    }
    f32x4 sa[4][4];
    #pragma unroll
    for (int ni = 0; ni < 4; ni++)
        #pragma unroll
        for (int mi = 0; mi < 4; mi++)
            sa[mi][ni] = __builtin_amdgcn_mfma_f32_16x16x32_bf16(qfr[mi], kfr[ni], (f32x4){0.f, 0.f, 0.f, 0.f}, 0, 0, 0);
    const float scale = 0.17677669529663687f;   // 32^-0.5
    #pragma unroll
    for (int mi = 0; mi < 4; mi++)
        #pragma unroll
        for (int ni = 0; ni < 4; ni++)
            #pragma unroll
            for (int r = 0; r < 4; r++) {
                int m = mi * 16 + ((lane >> 4) << 2) + r, n = ni * 16 + (lane & 15);
                if (m < 49 && n < 49) {
                    int rq = m / 7, cq = m - rq * 7, rk = n / 7, ck = n - rk * 7;
                    int ridx = (rq - rk + 6) * 13 + (cq - ck + 6);
                    ATT[h][m][n] = sa[mi][ni][r] * scale + rpb[ridx * 6 + h];
                }
            }
    __syncthreads();

    // ---- pl head-mix + shift mask (in place) ----
    int wi = widx >> 3, wj = widx & 7;
    for (int p = tid; p < 2401; p += 384) {
        int m = p / 49, n = p - m * 49;
        float a[6];
        #pragma unroll
        for (int g2 = 0; g2 < 6; g2++) a[g2] = ATT[g2][m][n];
        int rq = m / 7, cq = m - rq * 7, rk = n / 7, ck = n - rk * 7;
        int ghq = wi * 7 + rq, gwq = wj * 7 + cq, ghk = wi * 7 + rk, gwk = wj * 7 + ck;
        int regq = (ghq < 49 ? 0 : (ghq < 53 ? 1 : 2)) * 3 + (gwq < 49 ? 0 : (gwq < 53 ? 1 : 2));
        int regk = (ghk < 49 ? 0 : (ghk < 53 ? 1 : 2)) * 3 + (gwk < 49 ? 0 : (gwk < 53 ? 1 : 2));
        float msk = (regq != regk) ? -100.f : 0.f;
        #pragma unroll
        for (int g2 = 0; g2 < 6; g2++) {
            float v = plb[g2] + msk;
            #pragma unroll
            for (int h2 = 0; h2 < 6; h2++) v += a[h2] * plw[h2 * 6 + g2];
            ATT[g2][m][n] = v;
        }
    }
    __syncthreads();

    // ---- softmax: row-per-lane, one pass ----
    if (tid < 294) {
        int g2 = tid / 49, m = tid - g2 * 49;
        float* row = &ATT[g2][m][0];
        float mx = row[0];
        #pragma unroll
        for (int j = 1; j < 49; j++) mx = fmaxf(mx, row[j]);
        float e[49]; float sm = 0.f;
        #pragma unroll
        for (int j = 0; j < 49; j++) { e[j] = __expf(row[j] - mx); sm += e[j]; }
        float inv = 1.f / sm;
        #pragma unroll
        for (int j = 0; j < 49; j++) row[j] = e[j] * inv;
    }
    __syncthreads();

    // ---- pw head-mix (in place) ----
    for (int p = tid; p < 2401; p += 384) {
        int m = p / 49, n = p - m * 49;
        float a[6];
        #pragma unroll
        for (int g2 = 0; g2 < 6; g2++) a[g2] = ATT[g2][m][n];
        #pragma unroll
        for (int g2 = 0; g2 < 6; g2++) {
            float v = pwb[g2];
            #pragma unroll
            for (int h2 = 0; h2 < 6; h2++) v += a[h2] * pww[h2 * 6 + g2];
            ATT[g2][m][n] = v;
        }
    }
    __syncthreads();

    // ---- PV (per head): out[m][d] = sum_n P'[m][n] * V[n][d] ----
    f32x4 oa[4][2];
    #pragma unroll
    for (int mi = 0; mi < 4; mi++)
        #pragma unroll
        for (int ni = 0; ni < 2; ni++) oa[mi][ni] = (f32x4){0.f, 0.f, 0.f, 0.f};
    #pragma unroll
    for (int kst = 0; kst < 2; kst++) {
        #pragma unroll
        for (int mi = 0; mi < 4; mi++) {
            int m = mi * 16 + (lane & 15); if (m > 48) m = 48;
            const float* ap = &ATT[h][m][kst * 32 + ((lane >> 4) << 3)];
            bf16x8 afr;
            #pragma unroll
            for (int j = 0; j < 8; j++) afr[j] = (short)f2bf(ap[j]);
            #pragma unroll
            for (int ni = 0; ni < 2; ni++)
                oa[mi][ni] = __builtin_amdgcn_mfma_f32_16x16x32_bf16(afr, vfr[kst][ni], oa[mi][ni], 0, 0, 0);
        }
    }
    #pragma unroll
    for (int mi = 0; mi < 4; mi++)
        #pragma unroll
        for (int ni = 0; ni < 2; ni++)
            #pragma unroll
            for (int r = 0; r < 4; r++) {
                int m = mi * 16 + ((lane >> 4) << 2) + r, d = ni * 16 + (lane & 15);
                if (m < 49) aout[base + m * 192 + h * 32 + d] = f2bf(oa[mi][ni][r]);
            }
}

// ---------------- launcher ----------------
extern "C" void kernel_launch(void* const* d_in, const int* in_sizes, int n_in,
                              void* d_out, int out_size, void* d_ws, size_t ws_size,
                              hipStream_t stream)
{
    const float* x      = (const float*)d_in[0];
    const float* n1g    = (const float*)d_in[1];
    const float* n1b    = (const float*)d_in[2];
    const float* qkv_w  = (const float*)d_in[3];
    const float* qkv_b  = (const float*)d_in[4];
    const float* proj_w = (const float*)d_in[5];
    const float* proj_b = (const float*)d_in[6];
    const float* rpb    = (const float*)d_in[7];
    const float* pl_w   = (const float*)d_in[8];
    const float* pl_b   = (const float*)d_in[9];
    const float* pw_w   = (const float*)d_in[10];
    const float* pw_b   = (const float*)d_in[11];
    const float* n2g    = (const float*)d_in[12];
    const float* n2b    = (const float*)d_in[13];
    const float* fc1_w  = (const float*)d_in[14];
    const float* fc1_b  = (const float*)d_in[15];
    const float* fc2_w  = (const float*)d_in[16];
    const float* fc2_b  = (const float*)d_in[17];

    float* out   = (float*)d_out;   // f32: [xo | q | k | v], each OUTCH elements
    float* out_q = out + OUTCH;
    float* out_k = out + 2 * OUTCH;
    float* out_v = out + 3 * OUTCH;

    // ws: bufT 38,535,168 (bf16 TOKx192, time-shared win/attn-out/h2) | bufW 884,736
    char* ws = (char*)d_ws;
    unsigned short* bufT = (unsigned short*)ws;
    unsigned short* bufW = (unsigned short*)(ws + 38535168);

    k_prep_w<<<1728, 256, 0, stream>>>(qkv_w, proj_w, fc1_w, fc2_w, bufW);
    k_ln1<<<25088, 256, 0, stream>>>(x, n1g, n1b, bufT);                      // bufT = win
    k_gemm_qkv<<<dim3(9, 784), 256, 0, stream>>>(bufT, bufW, qkv_b, out_q);   // q/k/v f32
    k_attn<<<NWIN, 384, 0, stream>>>(out_q, out_k, out_v,
                                     rpb, pl_w, pl_b, pw_w, pw_b, bufT);      // bufT = attn out
    k_gemm_proj<<<dim3(3, 784), 256, 0, stream>>>(bufT, bufW + 110592, proj_b, x, out); // out[0:OUTCH] = pre-MLP xo
    k_ln2<<<25088, 256, 0, stream>>>(out, n2g, n2b, bufT);                    // bufT = h2
    k_mlp<<<1568, 256, 0, stream>>>(bufT, bufW + 147456, fc1_b, bufW + 294912, fc2_b, out);
}

// Round 7
// 500.170 us; speedup vs baseline: 1.9664x; 1.0786x over previous
//
#include <hip/hip_runtime.h>
#include <math.h>

// ---------------- problem constants ----------------
#define TOK   100352            // B * H * W  = 32*56*56  (= B_ * N = 2048*49)
#define OUTCH 19267584L         // TOK * 192, elements per output chunk (f32)
#define NWIN  2048

typedef __attribute__((ext_vector_type(4))) float f32x4;
typedef __attribute__((ext_vector_type(8))) short bf16x8;

__device__ __forceinline__ unsigned short f2bf(float f) {
    unsigned u = __builtin_bit_cast(unsigned, f);
    u += 0x7FFFu + ((u >> 16) & 1u);          // round-to-nearest-even
    return (unsigned short)(u >> 16);
}
__device__ __forceinline__ float bf2f(unsigned short s) {
    return __builtin_bit_cast(float, (unsigned)s << 16);
}

// ---------------- weight prep: transpose + bf16 cast ----------------
// layout in wt (bf16):
//  [0,110592)        qkv_wt [576][192]            (row-major, transposed)
//  [110592,147456)   proj_wt[192][192]            (row-major, transposed)
//  [147456,294912)   w1p: fc1 weights, MFMA fragment-packed for k_mlp GEMM1
//  [294912,442368)   w2p: fc2 weights, MFMA fragment-packed for k_mlp GEMM2
// Packed layout: instr = ((s*4 + wv)*3 + ni)*6 + ks  (288 slots), each slot
// 512 bf16 = lane*8 + j, so a wave's 16B/lane load is fully coalesced.
__global__ __launch_bounds__(256) void k_prep_w(const float* __restrict__ qkv_w,
                                                const float* __restrict__ proj_w,
                                                const float* __restrict__ fc1_w,
                                                const float* __restrict__ fc2_w,
                                                unsigned short* __restrict__ wt)
{
    int i = blockIdx.x * 256 + threadIdx.x;   // grid covers exactly 442368
    float v;
    if (i < 110592)       { int n = i / 192, k = i - n * 192;            v = qkv_w[k * 576 + n]; }
    else if (i < 147456)  { int j = i - 110592; int n = j / 192, k = j - n * 192; v = proj_w[k * 192 + n]; }
    else if (i < 294912) {
        int j2 = i - 147456;
        int instr = j2 >> 9, rem = j2 & 511, lane = rem >> 3, j = rem & 7;
        int ks = instr % 6, t = instr / 6;
        int ni = t % 3, t2 = t / 3;
        int wv = t2 & 3, s = t2 >> 2;
        int n = s * 192 + wv * 48 + ni * 16 + (lane & 15);   // fc1 out col in [0,768)
        int k = ks * 32 + ((lane >> 4) << 3) + j;            // k in [0,192)
        v = fc1_w[k * 768 + n];
    } else {
        int j2 = i - 294912;
        int instr = j2 >> 9, rem = j2 & 511, lane = rem >> 3, j = rem & 7;
        int ks = instr % 6, t = instr / 6;
        int ni = t % 3, t2 = t / 3;
        int wv = t2 & 3, s = t2 >> 2;
        int n = wv * 48 + ni * 16 + (lane & 15);             // fc2 out col in [0,192)
        int k = s * 192 + ks * 32 + ((lane >> 4) << 3) + j;  // hidden in [0,768)
        v = fc2_w[k * 192 + n];
    }
    wt[i] = f2bf(v);
}

// ---------------- LN1 + roll(-3,-3) + window partition -> bf16 win ----------------
__global__ __launch_bounds__(256) void k_ln1(const float* __restrict__ x,
                                             const float* __restrict__ g,
                                             const float* __restrict__ b,
                                             unsigned short* __restrict__ win)
{
    int lane = threadIdx.x & 63;
    int t = blockIdx.x * 4 + (threadIdx.x >> 6);      // window-token index
    int w = t / 49, n = t - w * 49;
    int bb = w >> 6, widx = w & 63;
    int wi = widx >> 3, wj = widx & 7;
    int r = n / 7, s = n - r * 7;
    int hh = wi * 7 + r + 3; if (hh >= 56) hh -= 56;  // roll(-SHIFT): rolled(h)=orig(h+3)
    int ww = wj * 7 + s + 3; if (ww >= 56) ww -= 56;
    const float* src = x + ((long)(bb * 56 + hh) * 56 + ww) * 192;
    float v0 = src[lane], v1 = src[lane + 64], v2 = src[lane + 128];
    float sum = v0 + v1 + v2;
    float sq  = v0 * v0 + v1 * v1 + v2 * v2;
    #pragma unroll
    for (int o = 32; o; o >>= 1) { sum += __shfl_xor(sum, o); sq += __shfl_xor(sq, o); }
    float mu = sum * (1.f / 192.f);
    float rs = rsqrtf(sq * (1.f / 192.f) - mu * mu + 1e-5f);
    unsigned short* dst = win + (long)t * 192;
    dst[lane]       = f2bf((v0 - mu) * rs * g[lane]       + b[lane]);
    dst[lane + 64]  = f2bf((v1 - mu) * rs * g[lane + 64]  + b[lane + 64]);
    dst[lane + 128] = f2bf((v2 - mu) * rs * g[lane + 128] + b[lane + 128]);
}

// ---------------- LN2: f32 xo -> bf16 h2 ----------------
__global__ __launch_bounds__(256) void k_ln2(const float* __restrict__ xo,
                                             const float* __restrict__ g,
                                             const float* __restrict__ b,
                                             unsigned short* __restrict__ h2)
{
    int lane = threadIdx.x & 63;
    long t = (long)blockIdx.x * 4 + (threadIdx.x >> 6);
    const float* src = xo + t * 192;
    float v0 = src[lane], v1 = src[lane + 64], v2 = src[lane + 128];
    float sum = v0 + v1 + v2;
    float sq  = v0 * v0 + v1 * v1 + v2 * v2;
    #pragma unroll
    for (int o = 32; o; o >>= 1) { sum += __shfl_xor(sum, o); sq += __shfl_xor(sq, o); }
    float mu = sum * (1.f / 192.f);
    float rs = rsqrtf(sq * (1.f / 192.f) - mu * mu + 1e-5f);
    unsigned short* dst = h2 + t * 192;
    dst[lane]       = f2bf((v0 - mu) * rs * g[lane]       + b[lane]);
    dst[lane + 64]  = f2bf((v1 - mu) * rs * g[lane + 64]  + b[lane + 64]);
    dst[lane + 128] = f2bf((v2 - mu) * rs * g[lane + 128] + b[lane + 128]);
}

// ---------------- shared GEMM main loop (qkv / proj) ----------------
// BM=128, BN=64, staged BK=192. A: [M][lda] bf16 row-major. Bt: [N][ldb] bf16 (transposed weights).
// LDS tiles XOR-swizzled (byte ^= (row&7)<<4) to keep ds_read_b128 conflict-free at 384 B row stride.
template<int KTOT>
__device__ __forceinline__ void gemm_tile(const unsigned short* __restrict__ A, int lda,
                                          const unsigned short* __restrict__ Bt, int ldb,
                                          int m0, int n0,
                                          unsigned short* lA, unsigned short* lB,
                                          f32x4 acc[4][2])
{
    const int tid = threadIdx.x, lane = tid & 63, wid = tid >> 6;
    const int wr = wid >> 1, wc = wid & 1;
    #pragma unroll
    for (int mi = 0; mi < 4; mi++)
        #pragma unroll
        for (int ni = 0; ni < 2; ni++) acc[mi][ni] = (f32x4){0.f, 0.f, 0.f, 0.f};

    for (int kt = 0; kt < KTOT; kt += 192) {
        __syncthreads();
        #pragma unroll
        for (int c = tid; c < 128 * 24; c += 256) {     // A: 128 rows x 24 16B-chunks
            int row = c / 24, k16 = c - row * 24;
            bf16x8 v = *(const bf16x8*)(A + (long)(m0 + row) * lda + kt + k16 * 8);
            *(bf16x8*)((char*)lA + row * 384 + ((k16 * 16) ^ ((row & 7) << 4))) = v;
        }
        #pragma unroll
        for (int c = tid; c < 64 * 24; c += 256) {      // B: 64 rows x 24 chunks
            int row = c / 24, k16 = c - row * 24;
            bf16x8 v = *(const bf16x8*)(Bt + (long)(n0 + row) * ldb + kt + k16 * 8);
            *(bf16x8*)((char*)lB + row * 384 + ((k16 * 16) ^ ((row & 7) << 4))) = v;
        }
        __syncthreads();
        #pragma unroll
        for (int ks = 0; ks < 6; ks++) {                // 192 / 32
            int kb = ks * 64 + ((lane >> 4) << 4);      // byte offset of this lane-group's 8 k-elems
            bf16x8 bfr[2];
            #pragma unroll
            for (int ni = 0; ni < 2; ni++) {
                int row = wc * 32 + ni * 16 + (lane & 15);
                bfr[ni] = *(const bf16x8*)((char*)lB + row * 384 + (kb ^ ((row & 7) << 4)));
            }
            #pragma unroll
            for (int mi = 0; mi < 4; mi++) {
                int row = wr * 64 + mi * 16 + (lane & 15);
                bf16x8 afr = *(const bf16x8*)((char*)lA + row * 384 + (kb ^ ((row & 7) << 4)));
                #pragma unroll
                for (int ni = 0; ni < 2; ni++)
                    acc[mi][ni] = __builtin_amdgcn_mfma_f32_16x16x32_bf16(afr, bfr[ni], acc[mi][ni], 0, 0, 0);
            }
        }
    }
}

// ---------------- QKV GEMM: win @ qkv_wt + b -> q/k/v chunks of d_out (f32) ----------------
__global__ __launch_bounds__(256) void k_gemm_qkv(const unsigned short* __restrict__ A,
                                                  const unsigned short* __restrict__ Bt,
                                                  const float* __restrict__ bias,
                                                  float* __restrict__ outq)
{
    __shared__ unsigned short lA[128 * 192];
    __shared__ unsigned short lB[64 * 192];
    f32x4 acc[4][2];
    int m0 = blockIdx.y * 128, n0 = blockIdx.x * 64;
    gemm_tile<192>(A, 192, Bt, 192, m0, n0, lA, lB, acc);
    int lane = threadIdx.x & 63, wid = threadIdx.x >> 6;
    int wr = wid >> 1, wc = wid & 1;
    #pragma unroll
    for (int mi = 0; mi < 4; mi++)
        #pragma unroll
        for (int ni = 0; ni < 2; ni++) {
            int gcol = n0 + wc * 32 + ni * 16 + (lane & 15);
            int ch = gcol / 192; int cc = gcol - ch * 192;
            float bv = bias[gcol];
            float* base = outq + (long)ch * OUTCH + cc;
            #pragma unroll
            for (int r = 0; r < 4; r++) {
                long grow = m0 + wr * 64 + mi * 16 + ((lane >> 4) << 2) + r;
                base[grow * 192] = acc[mi][ni][r] + bv;
            }
        }
}

// ---------------- proj GEMM + window reverse + roll(+3,+3) + residual -> xo f32 (d_out ch0) ---------
__global__ __launch_bounds__(256) void k_gemm_proj(const unsigned short* __restrict__ A,
                                                   const unsigned short* __restrict__ Bt,
                                                   const float* __restrict__ bias,
                                                   const float* __restrict__ x,
                                                   float* __restrict__ xo)
{
    __shared__ unsigned short lA[128 * 192];
    __shared__ unsigned short lB[64 * 192];
    f32x4 acc[4][2];
    int m0 = blockIdx.y * 128, n0 = blockIdx.x * 64;
    gemm_tile<192>(A, 192, Bt, 192, m0, n0, lA, lB, acc);
    int lane = threadIdx.x & 63, wid = threadIdx.x >> 6;
    int wr = wid >> 1, wc = wid & 1;
    #pragma unroll
    for (int mi = 0; mi < 4; mi++)
        #pragma unroll
        for (int ni = 0; ni < 2; ni++) {
            int gcol = n0 + wc * 32 + ni * 16 + (lane & 15);
            float bv = bias[gcol];
            #pragma unroll
            for (int r = 0; r < 4; r++) {
                int t = m0 + wr * 64 + mi * 16 + ((lane >> 4) << 2) + r;   // window token
                int w = t / 49, n = t - w * 49;
                int bb = w >> 6, widx = w & 63;
                int wi = widx >> 3, wj = widx & 7;
                int rr = n / 7, ss = n - rr * 7;
                int ho = wi * 7 + rr + 3; if (ho >= 56) ho -= 56;          // roll(+SHIFT)
                int wo = wj * 7 + ss + 3; if (wo >= 56) wo -= 56;
                long tp = ((long)(bb * 56 + ho) * 56 + wo);
                xo[tp * 192 + gcol] = x[tp * 192 + gcol] + acc[mi][ni][r] + bv;
            }
        }
}

// ---------------- fused MLP: xo += fc2(gelu(fc1(h2))) , BM=64, 4 slabs of 192 ----------------
// LDS 49,152 B -> 3 blocks/CU. B-operands read from fragment-packed weights:
// each load = packed_base + instr*512 + lane*8 -> fully coalesced 1 KB wave-load.
__global__ __launch_bounds__(256) void k_mlp(const unsigned short* __restrict__ h2,
                                             const unsigned short* __restrict__ w1p,  // packed, 288 slots
                                             const float* __restrict__ b1,
                                             const unsigned short* __restrict__ w2p,  // packed, 288 slots
                                             const float* __restrict__ b2,
                                             float* __restrict__ xo)
{
    __shared__ unsigned short lA[64 * 192];   // h2 tile, swizzled
    __shared__ unsigned short lH[64 * 192];   // gelu(fc1) slab, swizzled
    const int tid = threadIdx.x, lane = tid & 63, wv = tid >> 6;
    const long m0 = (long)blockIdx.x * 64;

    // stage A (64 rows x 24 chunks)
    #pragma unroll
    for (int c = tid; c < 64 * 24; c += 256) {
        int row = c / 24, k16 = c - row * 24;
        bf16x8 v = *(const bf16x8*)(h2 + (m0 + row) * 192 + k16 * 8);
        *(bf16x8*)((char*)lA + row * 384 + ((k16 * 16) ^ ((row & 7) << 4))) = v;
    }

    f32x4 acc2[4][3];
    #pragma unroll
    for (int mi = 0; mi < 4; mi++)
        #pragma unroll
        for (int ni = 0; ni < 3; ni++) acc2[mi][ni] = (f32x4){0.f, 0.f, 0.f, 0.f};
    __syncthreads();

    for (int s = 0; s < 4; s++) {
        // GEMM1: acc1 = A-tile @ W1[slab]; wave wv owns slab cols [wv*48, wv*48+48)
        f32x4 acc1[4][3];
        #pragma unroll
        for (int mi = 0; mi < 4; mi++)
            #pragma unroll
            for (int ni = 0; ni < 3; ni++) acc1[mi][ni] = (f32x4){0.f, 0.f, 0.f, 0.f};
        #pragma unroll
        for (int ks = 0; ks < 6; ks++) {
            int kb = ks * 64 + ((lane >> 4) << 4);
            bf16x8 bfr[3];
            #pragma unroll
            for (int ni = 0; ni < 3; ni++) {
                int instr = ((s * 4 + wv) * 3 + ni) * 6 + ks;
                bfr[ni] = *(const bf16x8*)(w1p + (instr << 9) + (lane << 3));
            }
            #pragma unroll
            for (int mi = 0; mi < 4; mi++) {
                int row = mi * 16 + (lane & 15);
                bf16x8 afr = *(const bf16x8*)((char*)lA + row * 384 + (kb ^ ((row & 7) << 4)));
                #pragma unroll
                for (int ni = 0; ni < 3; ni++)
                    acc1[mi][ni] = __builtin_amdgcn_mfma_f32_16x16x32_bf16(afr, bfr[ni], acc1[mi][ni], 0, 0, 0);
            }
        }
        __syncthreads();     // previous slab's GEMM2 reads of lH are done
        // GELU -> lH (swizzled scalar bf16 stores; XOR touches byte bits 4..6 only)
        #pragma unroll
        for (int mi = 0; mi < 4; mi++)
            #pragma unroll
            for (int ni = 0; ni < 3; ni++) {
                int col = wv * 48 + ni * 16 + (lane & 15);
                float bv = b1[s * 192 + col];
                #pragma unroll
                for (int r = 0; r < 4; r++) {
                    int row = mi * 16 + ((lane >> 4) << 2) + r;
                    float v = acc1[mi][ni][r] + bv;
                    float ge = 0.5f * v * (1.f + erff(v * 0.70710678118654752f));
                    *(unsigned short*)((char*)lH + row * 384 + ((2 * col) ^ ((row & 7) << 4))) = f2bf(ge);
                }
            }
        __syncthreads();
        // GEMM2 partial: acc2 += H_slab @ W2[:, slab]; wave wv owns out cols [wv*48, wv*48+48)
        #pragma unroll
        for (int ks = 0; ks < 6; ks++) {
            int kb = ks * 64 + ((lane >> 4) << 4);
            bf16x8 bfr[3];
            #pragma unroll
            for (int ni = 0; ni < 3; ni++) {
                int instr = ((s * 4 + wv) * 3 + ni) * 6 + ks;
                bfr[ni] = *(const bf16x8*)(w2p + (instr << 9) + (lane << 3));
            }
            #pragma unroll
            for (int mi = 0; mi < 4; mi++) {
                int row = mi * 16 + (lane & 15);
                bf16x8 afr = *(const bf16x8*)((char*)lH + row * 384 + (kb ^ ((row & 7) << 4)));
                #pragma unroll
                for (int ni = 0; ni < 3; ni++)
                    acc2[mi][ni] = __builtin_amdgcn_mfma_f32_16x16x32_bf16(afr, bfr[ni], acc2[mi][ni], 0, 0, 0);
            }
        }
    }
    // epilogue: xo += acc2 + b2 (in place, each element touched exactly once)
    #pragma unroll
    for (int mi = 0; mi < 4; mi++)
        #pragma unroll
        for (int ni = 0; ni < 3; ni++) {
            int gcol = wv * 48 + ni * 16 + (lane & 15);
            float bv = b2[gcol];
            #pragma unroll
            for (int r = 0; r < 4; r++) {
                long grow = m0 + mi * 16 + ((lane >> 4) << 2) + r;
                xo[grow * 192 + gcol] += acc2[mi][ni][r] + bv;
            }
        }
}

// ---------------- attention v2: one block (6 waves = 6 heads) per window ----------------
// LDS = ATT only: [6][49][67] f32 = 78,792 B  -> 2 blocks/CU.
// K/V/Q fragments load directly from global f32; V prefetched at kernel start.
#define ATS 67
__global__ __launch_bounds__(384) void k_attn(const float* __restrict__ qg,
                                              const float* __restrict__ kg,
                                              const float* __restrict__ vg,
                                              const float* __restrict__ rpb,
                                              const float* __restrict__ plw,
                                              const float* __restrict__ plb,
                                              const float* __restrict__ pww,
                                              const float* __restrict__ pwb,
                                              unsigned short* __restrict__ aout)
{
    __shared__ float ATT[6][49][ATS];          // scores; cols [49,64) zeroed for padded-K PV

    int w = blockIdx.x, widx = w & 63;
    int tid = threadIdx.x, lane = tid & 63, h = tid >> 6;   // wave id == head
    const long base = (long)w * 49 * 192;

    // ---- prefetch V fragments (B-operand of PV): n clamped to 48 (pad cols of P are 0)
    bf16x8 vfr[2][2];
    #pragma unroll
    for (int kst = 0; kst < 2; kst++)
        #pragma unroll
        for (int ni = 0; ni < 2; ni++) {
            int d = ni * 16 + (lane & 15);
            #pragma unroll
            for (int j = 0; j < 8; j++) {
                int n = kst * 32 + ((lane >> 4) << 3) + j; if (n > 48) n = 48;
                vfr[kst][ni][j] = (short)f2bf(vg[base + n * 192 + h * 32 + d]);
            }
        }

    // ---- zero ATT pad cols [49,64) ----
    for (int c = tid; c < 6 * 49 * 15; c += 384) {
        int g2 = c / (49 * 15), rem = c - g2 * (49 * 15);
        int m = rem / 15, n = 49 + (rem - m * 15);
        ATT[g2][m][n] = 0.f;
    }

    // ---- QK^T (per head), fragments straight from global ----
    bf16x8 qfr[4], kfr[4];
    #pragma unroll
    for (int mi = 0; mi < 4; mi++) {
        int m = mi * 16 + (lane & 15); if (m > 48) m = 48;
        const float* qp = qg + base + m * 192 + h * 32 + ((lane >> 4) << 3);
        #pragma unroll
        for (int j = 0; j < 8; j++) qfr[mi][j] = (short)f2bf(qp[j]);
    }
    #pragma unroll
    for (int ni = 0; ni < 4; ni++) {
        int n = ni * 16 + (lane & 15); if (n > 48) n = 48;
        const float* kp = kg + base + n * 192 + h * 32 + ((lane >> 4) << 3);
        #pragma unroll
        for (int j = 0; j < 8; j++) kfr[ni][j] = (short)f2bf(kp[j]);
    }
    f32x4 sa[4][4];
    #pragma unroll
    for (int ni = 0; ni < 4; ni++)
        #pragma unroll
        for (int mi = 0; mi < 4; mi++)
            sa[mi][ni] = __builtin_amdgcn_mfma_f32_16x16x32_bf16(qfr[mi], kfr[ni], (f32x4){0.f, 0.f, 0.f, 0.f}, 0, 0, 0);
    const float scale = 0.17677669529663687f;   // 32^-0.5
    #pragma unroll
    for (int mi = 0; mi < 4; mi++)
        #pragma unroll
        for (int ni = 0; ni < 4; ni++)
            #pragma unroll
            for (int r = 0; r < 4; r++) {
                int m = mi * 16 + ((lane >> 4) << 2) + r, n = ni * 16 + (lane & 15);
                if (m < 49 && n < 49) {
                    int rq = m / 7, cq = m - rq * 7, rk = n / 7, ck = n - rk * 7;
                    int ridx = (rq - rk + 6) * 13 + (cq - ck + 6);
                    ATT[h][m][n] = sa[mi][ni][r] * scale + rpb[ridx * 6 + h];
                }
            }
    __syncthreads();

    // ---- pl head-mix + shift mask (in place) ----
    int wi = widx >> 3, wj = widx & 7;
    for (int p = tid; p < 2401; p += 384) {
        int m = p / 49, n = p - m * 49;
        float a[6];
        #pragma unroll
        for (int g2 = 0; g2 < 6; g2++) a[g2] = ATT[g2][m][n];
        int rq = m / 7, cq = m - rq * 7, rk = n / 7, ck = n - rk * 7;
        int ghq = wi * 7 + rq, gwq = wj * 7 + cq, ghk = wi * 7 + rk, gwk = wj * 7 + ck;
        int regq = (ghq < 49 ? 0 : (ghq < 53 ? 1 : 2)) * 3 + (gwq < 49 ? 0 : (gwq < 53 ? 1 : 2));
        int regk = (ghk < 49 ? 0 : (ghk < 53 ? 1 : 2)) * 3 + (gwk < 49 ? 0 : (gwk < 53 ? 1 : 2));
        float msk = (regq != regk) ? -100.f : 0.f;
        #pragma unroll
        for (int g2 = 0; g2 < 6; g2++) {
            float v = plb[g2] + msk;
            #pragma unroll
            for (int h2 = 0; h2 < 6; h2++) v += a[h2] * plw[h2 * 6 + g2];
            ATT[g2][m][n] = v;
        }
    }
    __syncthreads();

    // ---- softmax: row-per-lane, one pass ----
    if (tid < 294) {
        int g2 = tid / 49, m = tid - g2 * 49;
        float* row = &ATT[g2][m][0];
        float mx = row[0];
        #pragma unroll
        for (int j = 1; j < 49; j++) mx = fmaxf(mx, row[j]);
        float e[49]; float sm = 0.f;
        #pragma unroll
        for (int j = 0; j < 49; j++) { e[j] = __expf(row[j] - mx); sm += e[j]; }
        float inv = 1.f / sm;
        #pragma unroll
        for (int j = 0; j < 49; j++) row[j] = e[j] * inv;
    }
    __syncthreads();

    // ---- pw head-mix (in place) ----
    for (int p = tid; p < 2401; p += 384) {
        int m = p / 49, n = p - m * 49;
        float a[6];
        #pragma unroll
        for (int g2 = 0; g2 < 6; g2++) a[g2] = ATT[g2][m][n];
        #pragma unroll
        for (int g2 = 0; g2 < 6; g2++) {
            float v = pwb[g2];
            #pragma unroll
            for (int h2 = 0; h2 < 6; h2++) v += a[h2] * pww[h2 * 6 + g2];
            ATT[g2][m][n] = v;
        }
    }
    __syncthreads();

    // ---- PV (per head): out[m][d] = sum_n P'[m][n] * V[n][d] ----
    f32x4 oa[4][2];
    #pragma unroll
    for (int mi = 0; mi < 4; mi++)
        #pragma unroll
        for (int ni = 0; ni < 2; ni++) oa[mi][ni] = (f32x4){0.f, 0.f, 0.f, 0.f};
    #pragma unroll
    for (int kst = 0; kst < 2; kst++) {
        #pragma unroll
        for (int mi = 0; mi < 4; mi++) {
            int m = mi * 16 + (lane & 15); if (m > 48) m = 48;
            const float* ap = &ATT[h][m][kst * 32 + ((lane >> 4) << 3)];
            bf16x8 afr;
            #pragma unroll
            for (int j = 0; j < 8; j++) afr[j] = (short)f2bf(ap[j]);
            #pragma unroll
            for (int ni = 0; ni < 2; ni++)
                oa[mi][ni] = __builtin_amdgcn_mfma_f32_16x16x32_bf16(afr, vfr[kst][ni], oa[mi][ni], 0, 0, 0);
        }
    }
    #pragma unroll
    for (int mi = 0; mi < 4; mi++)
        #pragma unroll
        for (int ni = 0; ni < 2; ni++)
            #pragma unroll
            for (int r = 0; r < 4; r++) {
                int m = mi * 16 + ((lane >> 4) << 2) + r, d = ni * 16 + (lane & 15);
                if (m < 49) aout[base + m * 192 + h * 32 + d] = f2bf(oa[mi][ni][r]);
            }
}

// ---------------- launcher ----------------
extern "C" void kernel_launch(void* const* d_in, const int* in_sizes, int n_in,
                              void* d_out, int out_size, void* d_ws, size_t ws_size,
                              hipStream_t stream)
{
    const float* x      = (const float*)d_in[0];
    const float* n1g    = (const float*)d_in[1];
    const float* n1b    = (const float*)d_in[2];
    const float* qkv_w  = (const float*)d_in[3];
    const float* qkv_b  = (const float*)d_in[4];
    const float* proj_w = (const float*)d_in[5];
    const float* proj_b = (const float*)d_in[6];
    const float* rpb    = (const float*)d_in[7];
    const float* pl_w   = (const float*)d_in[8];
    const float* pl_b   = (const float*)d_in[9];
    const float* pw_w   = (const float*)d_in[10];
    const float* pw_b   = (const float*)d_in[11];
    const float* n2g    = (const float*)d_in[12];
    const float* n2b    = (const float*)d_in[13];
    const float* fc1_w  = (const float*)d_in[14];
    const float* fc1_b  = (const float*)d_in[15];
    const float* fc2_w  = (const float*)d_in[16];
    const float* fc2_b  = (const float*)d_in[17];

    float* out   = (float*)d_out;   // f32: [xo | q | k | v], each OUTCH elements
    float* out_q = out + OUTCH;
    float* out_k = out + 2 * OUTCH;
    float* out_v = out + 3 * OUTCH;

    // ws: bufT 38,535,168 (bf16 TOKx192, time-shared win/attn-out/h2) | bufW 884,736
    char* ws = (char*)d_ws;
    unsigned short* bufT = (unsigned short*)ws;
    unsigned short* bufW = (unsigned short*)(ws + 38535168);

    k_prep_w<<<1728, 256, 0, stream>>>(qkv_w, proj_w, fc1_w, fc2_w, bufW);
    k_ln1<<<25088, 256, 0, stream>>>(x, n1g, n1b, bufT);                      // bufT = win
    k_gemm_qkv<<<dim3(9, 784), 256, 0, stream>>>(bufT, bufW, qkv_b, out_q);   // q/k/v f32
    k_attn<<<NWIN, 384, 0, stream>>>(out_q, out_k, out_v,
                                     rpb, pl_w, pl_b, pw_w, pw_b, bufT);      // bufT = attn out
    k_gemm_proj<<<dim3(3, 784), 256, 0, stream>>>(bufT, bufW + 110592, proj_b, x, out); // out[0:OUTCH] = pre-MLP xo
    k_ln2<<<25088, 256, 0, stream>>>(out, n2g, n2b, bufT);                    // bufT = h2
    k_mlp<<<1568, 256, 0, stream>>>(bufT, bufW + 147456, fc1_b, bufW + 294912, fc2_b, out);
}

// Round 8
// 457.671 us; speedup vs baseline: 2.1490x; 1.0929x over previous
//
#include <hip/hip_runtime.h>
#include <math.h>

// ---------------- problem constants ----------------
#define TOK   100352            // B * H * W  = 32*56*56  (= B_ * N = 2048*49)
#define OUTCH 19267584L         // TOK * 192, elements per output chunk (f32)
#define NWIN  2048

typedef __attribute__((ext_vector_type(4))) float f32x4;
typedef __attribute__((ext_vector_type(8))) short bf16x8;

__device__ __forceinline__ unsigned short f2bf(float f) {
    unsigned u = __builtin_bit_cast(unsigned, f);
    u += 0x7FFFu + ((u >> 16) & 1u);          // round-to-nearest-even
    return (unsigned short)(u >> 16);
}
__device__ __forceinline__ float bf2f(unsigned short s) {
    return __builtin_bit_cast(float, (unsigned)s << 16);
}

// ---------------- weight prep: all four weight matrices MFMA fragment-packed ----------------
// wt layout (bf16):
//  [0,110592)        qkvp: 216 slots  instr=((s*4+wv)*3+ni)*6+ks, s<3
//  [110592,147456)   projp: 72 slots  instr=(wv*3+ni)*6+ks
//  [147456,294912)   w1p:  288 slots  instr=((s*4+wv)*3+ni)*6+ks, s<4
//  [294912,442368)   w2p:  288 slots  (same index, k runs over 768)
// Each slot = 512 bf16 = lane*8+j  -> wave load = coalesced 1 KB.
__global__ __launch_bounds__(256) void k_prep_w(const float* __restrict__ qkv_w,
                                                const float* __restrict__ proj_w,
                                                const float* __restrict__ fc1_w,
                                                const float* __restrict__ fc2_w,
                                                unsigned short* __restrict__ wt)
{
    int i = blockIdx.x * 256 + threadIdx.x;   // grid covers exactly 442368
    float v;
    if (i < 110592) {
        int instr = i >> 9, rem = i & 511, lane = rem >> 3, j = rem & 7;
        int ks = instr % 6, t = instr / 6;
        int ni = t % 3, t2 = t / 3;
        int wv = t2 & 3, s = t2 >> 2;                        // s in [0,3)
        int n = s * 192 + wv * 48 + ni * 16 + (lane & 15);   // out col in [0,576)
        int k = ks * 32 + ((lane >> 4) << 3) + j;            // k in [0,192)
        v = qkv_w[k * 576 + n];
    } else if (i < 147456) {
        int j2 = i - 110592;
        int instr = j2 >> 9, rem = j2 & 511, lane = rem >> 3, j = rem & 7;
        int ks = instr % 6, t = instr / 6;
        int ni = t % 3, wv = t / 3;                          // wv in [0,4)
        int n = wv * 48 + ni * 16 + (lane & 15);             // out col in [0,192)
        int k = ks * 32 + ((lane >> 4) << 3) + j;
        v = proj_w[k * 192 + n];
    } else if (i < 294912) {
        int j2 = i - 147456;
        int instr = j2 >> 9, rem = j2 & 511, lane = rem >> 3, j = rem & 7;
        int ks = instr % 6, t = instr / 6;
        int ni = t % 3, t2 = t / 3;
        int wv = t2 & 3, s = t2 >> 2;
        int n = s * 192 + wv * 48 + ni * 16 + (lane & 15);   // fc1 out col in [0,768)
        int k = ks * 32 + ((lane >> 4) << 3) + j;            // k in [0,192)
        v = fc1_w[k * 768 + n];
    } else {
        int j2 = i - 294912;
        int instr = j2 >> 9, rem = j2 & 511, lane = rem >> 3, j = rem & 7;
        int ks = instr % 6, t = instr / 6;
        int ni = t % 3, t2 = t / 3;
        int wv = t2 & 3, s = t2 >> 2;
        int n = wv * 48 + ni * 16 + (lane & 15);             // fc2 out col in [0,192)
        int k = s * 192 + ks * 32 + ((lane >> 4) << 3) + j;  // hidden in [0,768)
        v = fc2_w[k * 192 + n];
    }
    wt[i] = f2bf(v);
}

// ---------------- QKV GEMM with fused LN1 + roll + window partition ----------------
// grid (3, 1568): slab s = q/k/v selector, 64 window-token rows per block.
// A staged from x with on-the-fly LayerNorm (4 threads/row, shfl combine).
__global__ __launch_bounds__(256) void k_qkv(const float* __restrict__ x,
                                             const float* __restrict__ g,
                                             const float* __restrict__ b,
                                             const unsigned short* __restrict__ wp,   // qkvp
                                             const float* __restrict__ bias,          // [576]
                                             float* __restrict__ outq)                // q chunk base
{
    __shared__ unsigned short lA[64 * 192];
    const int tid = threadIdx.x, lane = tid & 63, wv = tid >> 6;
    const int s = blockIdx.x;
    const long m0 = (long)blockIdx.y * 64;

    // ---- stage + LN1: row r = tid/4, cols [(tid&3)*48, +48) ----
    {
        int r = tid >> 2, c0 = (tid & 3) * 48;
        int t = (int)m0 + r;
        int w = t / 49, n = t - w * 49;
        int bb = w >> 6, widx = w & 63;
        int wi = widx >> 3, wj = widx & 7;
        int rr = n / 7, ss = n - rr * 7;
        int hh = wi * 7 + rr + 3; if (hh >= 56) hh -= 56;   // roll(-SHIFT)
        int ww = wj * 7 + ss + 3; if (ww >= 56) ww -= 56;
        const f32x4* sp = (const f32x4*)(x + ((long)(bb * 56 + hh) * 56 + ww) * 192 + c0);
        f32x4 vv[12];
        float sum = 0.f, sq = 0.f;
        #pragma unroll
        for (int i = 0; i < 12; i++) {
            vv[i] = sp[i];
            #pragma unroll
            for (int j = 0; j < 4; j++) { sum += vv[i][j]; sq += vv[i][j] * vv[i][j]; }
        }
        sum += __shfl_xor(sum, 1); sq += __shfl_xor(sq, 1);
        sum += __shfl_xor(sum, 2); sq += __shfl_xor(sq, 2);
        float mu = sum * (1.f / 192.f);
        float rs = rsqrtf(sq * (1.f / 192.f) - mu * mu + 1e-5f);
        #pragma unroll
        for (int i = 0; i < 6; i++) {
            bf16x8 o8;
            #pragma unroll
            for (int j = 0; j < 8; j++) {
                int idx = i * 8 + j, c = c0 + idx;
                o8[j] = (short)f2bf((vv[idx >> 2][idx & 3] - mu) * rs * g[c] + b[c]);
            }
            *(bf16x8*)((char*)lA + r * 384 + ((2 * (c0 + i * 8)) ^ ((r & 7) << 4))) = o8;
        }
    }
    __syncthreads();

    // ---- barrier-free K loop, packed B ----
    f32x4 acc[4][3];
    #pragma unroll
    for (int mi = 0; mi < 4; mi++)
        #pragma unroll
        for (int ni = 0; ni < 3; ni++) acc[mi][ni] = (f32x4){0.f, 0.f, 0.f, 0.f};
    #pragma unroll
    for (int ks = 0; ks < 6; ks++) {
        int kb = ks * 64 + ((lane >> 4) << 4);
        bf16x8 bfr[3];
        #pragma unroll
        for (int ni = 0; ni < 3; ni++) {
            int instr = ((s * 4 + wv) * 3 + ni) * 6 + ks;
            bfr[ni] = *(const bf16x8*)(wp + (instr << 9) + (lane << 3));
        }
        #pragma unroll
        for (int mi = 0; mi < 4; mi++) {
            int row = mi * 16 + (lane & 15);
            bf16x8 afr = *(const bf16x8*)((char*)lA + row * 384 + (kb ^ ((row & 7) << 4)));
            #pragma unroll
            for (int ni = 0; ni < 3; ni++)
                acc[mi][ni] = __builtin_amdgcn_mfma_f32_16x16x32_bf16(afr, bfr[ni], acc[mi][ni], 0, 0, 0);
        }
    }

    // ---- epilogue: f32 q/k/v chunk s ----
    #pragma unroll
    for (int mi = 0; mi < 4; mi++)
        #pragma unroll
        for (int ni = 0; ni < 3; ni++) {
            int gc = wv * 48 + ni * 16 + (lane & 15);
            float bv = bias[s * 192 + gc];
            #pragma unroll
            for (int r4 = 0; r4 < 4; r4++) {
                long lr = mi * 16 + ((lane >> 4) << 2) + r4;
                outq[(long)s * OUTCH + (m0 + lr) * 192 + gc] = acc[mi][ni][r4] + bv;
            }
        }
}

// ---------------- proj GEMM + residual + fused LN2 ----------------
// A = attn-out (SPATIAL order, bf16). Block covers 64 rows x all 192 cols.
// Epilogue: xo = x + proj + bias -> LDS tile + global; then per-row LN2 -> h2
// written IN PLACE over the attn-out buffer (same 64 rows this block consumed).
__global__ __launch_bounds__(256) void k_proj(const unsigned short* __restrict__ aspat,
                                              const unsigned short* __restrict__ wp,   // projp
                                              const float* __restrict__ pbias,
                                              const float* __restrict__ x,
                                              const float* __restrict__ g2,
                                              const float* __restrict__ b2,
                                              float* __restrict__ xo,
                                              unsigned short* __restrict__ h2)
{
    __shared__ unsigned short lA[64 * 192];
    __shared__ float xoT[64][196];             // stride 196 -> 2-way banks only
    const int tid = threadIdx.x, lane = tid & 63, wv = tid >> 6;
    const long m0 = (long)blockIdx.x * 64;

    #pragma unroll
    for (int c = tid; c < 64 * 24; c += 256) {
        int row = c / 24, k16 = c - row * 24;
        bf16x8 v = *(const bf16x8*)(aspat + (m0 + row) * 192 + k16 * 8);
        *(bf16x8*)((char*)lA + row * 384 + ((k16 * 16) ^ ((row & 7) << 4))) = v;
    }
    __syncthreads();

    f32x4 acc[4][3];
    #pragma unroll
    for (int mi = 0; mi < 4; mi++)
        #pragma unroll
        for (int ni = 0; ni < 3; ni++) acc[mi][ni] = (f32x4){0.f, 0.f, 0.f, 0.f};
    #pragma unroll
    for (int ks = 0; ks < 6; ks++) {
        int kb = ks * 64 + ((lane >> 4) << 4);
        bf16x8 bfr[3];
        #pragma unroll
        for (int ni = 0; ni < 3; ni++) {
            int instr = (wv * 3 + ni) * 6 + ks;
            bfr[ni] = *(const bf16x8*)(wp + (instr << 9) + (lane << 3));
        }
        #pragma unroll
        for (int mi = 0; mi < 4; mi++) {
            int row = mi * 16 + (lane & 15);
            bf16x8 afr = *(const bf16x8*)((char*)lA + row * 384 + (kb ^ ((row & 7) << 4)));
            #pragma unroll
            for (int ni = 0; ni < 3; ni++)
                acc[mi][ni] = __builtin_amdgcn_mfma_f32_16x16x32_bf16(afr, bfr[ni], acc[mi][ni], 0, 0, 0);
        }
    }

    // epilogue: xo = x + proj + bias  (LDS tile + global write)
    #pragma unroll
    for (int mi = 0; mi < 4; mi++)
        #pragma unroll
        for (int ni = 0; ni < 3; ni++) {
            int gc = wv * 48 + ni * 16 + (lane & 15);
            float bv = pbias[gc];
            #pragma unroll
            for (int r4 = 0; r4 < 4; r4++) {
                int lr = mi * 16 + ((lane >> 4) << 2) + r4;
                long grow = m0 + lr;
                float xv = x[grow * 192 + gc] + acc[mi][ni][r4] + bv;
                xoT[lr][gc] = xv;
                xo[grow * 192 + gc] = xv;
            }
        }
    __syncthreads();

    // LN2: row r = tid/4, cols [(tid&3)*48, +48); write h2 in place
    {
        int r = tid >> 2, c0 = (tid & 3) * 48;
        float vv[48];
        float sum = 0.f, sq = 0.f;
        #pragma unroll
        for (int i = 0; i < 48; i++) { vv[i] = xoT[r][c0 + i]; sum += vv[i]; sq += vv[i] * vv[i]; }
        sum += __shfl_xor(sum, 1); sq += __shfl_xor(sq, 1);
        sum += __shfl_xor(sum, 2); sq += __shfl_xor(sq, 2);
        float mu = sum * (1.f / 192.f);
        float rs = rsqrtf(sq * (1.f / 192.f) - mu * mu + 1e-5f);
        #pragma unroll
        for (int i = 0; i < 6; i++) {
            bf16x8 o8;
            #pragma unroll
            for (int j = 0; j < 8; j++) {
                int c = c0 + i * 8 + j;
                o8[j] = (short)f2bf((vv[i * 8 + j] - mu) * rs * g2[c] + b2[c]);
            }
            *(bf16x8*)(h2 + (m0 + r) * 192 + c0 + i * 8) = o8;
        }
    }
}

// ---------------- fused MLP: xo += fc2(gelu(fc1(h2))) , BM=64, 4 slabs of 192 ----------------
__global__ __launch_bounds__(256) void k_mlp(const unsigned short* __restrict__ h2,
                                             const unsigned short* __restrict__ w1p,
                                             const float* __restrict__ b1,
                                             const unsigned short* __restrict__ w2p,
                                             const float* __restrict__ b2,
                                             float* __restrict__ xo)
{
    __shared__ unsigned short lA[64 * 192];   // h2 tile, swizzled
    __shared__ unsigned short lH[64 * 192];   // gelu(fc1) slab, swizzled
    const int tid = threadIdx.x, lane = tid & 63, wv = tid >> 6;
    const long m0 = (long)blockIdx.x * 64;

    #pragma unroll
    for (int c = tid; c < 64 * 24; c += 256) {
        int row = c / 24, k16 = c - row * 24;
        bf16x8 v = *(const bf16x8*)(h2 + (m0 + row) * 192 + k16 * 8);
        *(bf16x8*)((char*)lA + row * 384 + ((k16 * 16) ^ ((row & 7) << 4))) = v;
    }

    f32x4 acc2[4][3];
    #pragma unroll
    for (int mi = 0; mi < 4; mi++)
        #pragma unroll
        for (int ni = 0; ni < 3; ni++) acc2[mi][ni] = (f32x4){0.f, 0.f, 0.f, 0.f};
    __syncthreads();

    for (int s = 0; s < 4; s++) {
        f32x4 acc1[4][3];
        #pragma unroll
        for (int mi = 0; mi < 4; mi++)
            #pragma unroll
            for (int ni = 0; ni < 3; ni++) acc1[mi][ni] = (f32x4){0.f, 0.f, 0.f, 0.f};
        #pragma unroll
        for (int ks = 0; ks < 6; ks++) {
            int kb = ks * 64 + ((lane >> 4) << 4);
            bf16x8 bfr[3];
            #pragma unroll
            for (int ni = 0; ni < 3; ni++) {
                int instr = ((s * 4 + wv) * 3 + ni) * 6 + ks;
                bfr[ni] = *(const bf16x8*)(w1p + (instr << 9) + (lane << 3));
            }
            #pragma unroll
            for (int mi = 0; mi < 4; mi++) {
                int row = mi * 16 + (lane & 15);
                bf16x8 afr = *(const bf16x8*)((char*)lA + row * 384 + (kb ^ ((row & 7) << 4)));
                #pragma unroll
                for (int ni = 0; ni < 3; ni++)
                    acc1[mi][ni] = __builtin_amdgcn_mfma_f32_16x16x32_bf16(afr, bfr[ni], acc1[mi][ni], 0, 0, 0);
            }
        }
        __syncthreads();     // previous slab's GEMM2 reads of lH are done
        #pragma unroll
        for (int mi = 0; mi < 4; mi++)
            #pragma unroll
            for (int ni = 0; ni < 3; ni++) {
                int col = wv * 48 + ni * 16 + (lane & 15);
                float bv = b1[s * 192 + col];
                #pragma unroll
                for (int r = 0; r < 4; r++) {
                    int row = mi * 16 + ((lane >> 4) << 2) + r;
                    float v = acc1[mi][ni][r] + bv;
                    float ge = 0.5f * v * (1.f + erff(v * 0.70710678118654752f));
                    *(unsigned short*)((char*)lH + row * 384 + ((2 * col) ^ ((row & 7) << 4))) = f2bf(ge);
                }
            }
        __syncthreads();
        #pragma unroll
        for (int ks = 0; ks < 6; ks++) {
            int kb = ks * 64 + ((lane >> 4) << 4);
            bf16x8 bfr[3];
            #pragma unroll
            for (int ni = 0; ni < 3; ni++) {
                int instr = ((s * 4 + wv) * 3 + ni) * 6 + ks;
                bfr[ni] = *(const bf16x8*)(w2p + (instr << 9) + (lane << 3));
            }
            #pragma unroll
            for (int mi = 0; mi < 4; mi++) {
                int row = mi * 16 + (lane & 15);
                bf16x8 afr = *(const bf16x8*)((char*)lH + row * 384 + (kb ^ ((row & 7) << 4)));
                #pragma unroll
                for (int ni = 0; ni < 3; ni++)
                    acc2[mi][ni] = __builtin_amdgcn_mfma_f32_16x16x32_bf16(afr, bfr[ni], acc2[mi][ni], 0, 0, 0);
            }
        }
    }
    #pragma unroll
    for (int mi = 0; mi < 4; mi++)
        #pragma unroll
        for (int ni = 0; ni < 3; ni++) {
            int gcol = wv * 48 + ni * 16 + (lane & 15);
            float bv = b2[gcol];
            #pragma unroll
            for (int r = 0; r < 4; r++) {
                long grow = m0 + mi * 16 + ((lane >> 4) << 2) + r;
                xo[grow * 192 + gcol] += acc2[mi][ni][r] + bv;
            }
        }
}

// ---------------- attention: one block (6 waves = 6 heads) per window ----------------
// Epilogue now applies window-reverse + roll(+3,+3): output is SPATIAL-ordered bf16.
#define ATS 67
__global__ __launch_bounds__(384) void k_attn(const float* __restrict__ qg,
                                              const float* __restrict__ kg,
                                              const float* __restrict__ vg,
                                              const float* __restrict__ rpb,
                                              const float* __restrict__ plw,
                                              const float* __restrict__ plb,
                                              const float* __restrict__ pww,
                                              const float* __restrict__ pwb,
                                              unsigned short* __restrict__ aout)
{
    __shared__ float ATT[6][49][ATS];          // scores; cols [49,64) zeroed for padded-K PV

    int w = blockIdx.x, widx = w & 63;
    int tid = threadIdx.x, lane = tid & 63, h = tid >> 6;   // wave id == head
    const long base = (long)w * 49 * 192;

    // ---- prefetch V fragments (B-operand of PV): n clamped to 48 (pad cols of P are 0)
    bf16x8 vfr[2][2];
    #pragma unroll
    for (int kst = 0; kst < 2; kst++)
        #pragma unroll
        for (int ni = 0; ni < 2; ni++) {
            int d = ni * 16 + (lane & 15);
            #pragma unroll
            for (int j = 0; j < 8; j++) {
                int n = kst * 32 + ((lane >> 4) << 3) + j; if (n > 48) n = 48;
                vfr[kst][ni][j] = (short)f2bf(vg[base + n * 192 + h * 32 + d]);
            }
        }

    // ---- zero ATT pad cols [49,64) ----
    for (int c = tid; c < 6 * 49 * 15; c += 384) {
        int g2 = c / (49 * 15), rem = c - g2 * (49 * 15);
        int m = rem / 15, n = 49 + (rem - m * 15);
        ATT[g2][m][n] = 0.f;
    }

    // ---- QK^T (per head), fragments straight from global ----
    bf16x8 qfr[4], kfr[4];
    #pragma unroll
    for (int mi = 0; mi < 4; mi++) {
        int m = mi * 16 + (lane & 15); if (m > 48) m = 48;
        const float* qp = qg + base + m * 192 + h * 32 + ((lane >> 4) << 3);
        #pragma unroll
        for (int j = 0; j < 8; j++) qfr[mi][j] = (short)f2bf(qp[j]);
    }
    #pragma unroll
    for (int ni = 0; ni < 4; ni++) {
        int n = ni * 16 + (lane & 15); if (n > 48) n = 48;
        const float* kp = kg + base + n * 192 + h * 32 + ((lane >> 4) << 3);
        #pragma unroll
        for (int j = 0; j < 8; j++) kfr[ni][j] = (short)f2bf(kp[j]);
    }
    f32x4 sa[4][4];
    #pragma unroll
    for (int ni = 0; ni < 4; ni++)
        #pragma unroll
        for (int mi = 0; mi < 4; mi++)
            sa[mi][ni] = __builtin_amdgcn_mfma_f32_16x16x32_bf16(qfr[mi], kfr[ni], (f32x4){0.f, 0.f, 0.f, 0.f}, 0, 0, 0);
    const float scale = 0.17677669529663687f;   // 32^-0.5
    #pragma unroll
    for (int mi = 0; mi < 4; mi++)
        #pragma unroll
        for (int ni = 0; ni < 4; ni++)
            #pragma unroll
            for (int r = 0; r < 4; r++) {
                int m = mi * 16 + ((lane >> 4) << 2) + r, n = ni * 16 + (lane & 15);
                if (m < 49 && n < 49) {
                    int rq = m / 7, cq = m - rq * 7, rk = n / 7, ck = n - rk * 7;
                    int ridx = (rq - rk + 6) * 13 + (cq - ck + 6);
                    ATT[h][m][n] = sa[mi][ni][r] * scale + rpb[ridx * 6 + h];
                }
            }
    __syncthreads();

    // ---- pl head-mix + shift mask (in place) ----
    int wi = widx >> 3, wj = widx & 7;
    for (int p = tid; p < 2401; p += 384) {
        int m = p / 49, n = p - m * 49;
        float a[6];
        #pragma unroll
        for (int g2 = 0; g2 < 6; g2++) a[g2] = ATT[g2][m][n];
        int rq = m / 7, cq = m - rq * 7, rk = n / 7, ck = n - rk * 7;
        int ghq = wi * 7 + rq, gwq = wj * 7 + cq, ghk = wi * 7 + rk, gwk = wj * 7 + ck;
        int regq = (ghq < 49 ? 0 : (ghq < 53 ? 1 : 2)) * 3 + (gwq < 49 ? 0 : (gwq < 53 ? 1 : 2));
        int regk = (ghk < 49 ? 0 : (ghk < 53 ? 1 : 2)) * 3 + (gwk < 49 ? 0 : (gwk < 53 ? 1 : 2));
        float msk = (regq != regk) ? -100.f : 0.f;
        #pragma unroll
        for (int g2 = 0; g2 < 6; g2++) {
            float v = plb[g2] + msk;
            #pragma unroll
            for (int h2 = 0; h2 < 6; h2++) v += a[h2] * plw[h2 * 6 + g2];
            ATT[g2][m][n] = v;
        }
    }
    __syncthreads();

    // ---- softmax: row-per-lane, one pass ----
    if (tid < 294) {
        int g2 = tid / 49, m = tid - g2 * 49;
        float* row = &ATT[g2][m][0];
        float mx = row[0];
        #pragma unroll
        for (int j = 1; j < 49; j++) mx = fmaxf(mx, row[j]);
        float e[49]; float sm = 0.f;
        #pragma unroll
        for (int j = 0; j < 49; j++) { e[j] = __expf(row[j] - mx); sm += e[j]; }
        float inv = 1.f / sm;
        #pragma unroll
        for (int j = 0; j < 49; j++) row[j] = e[j] * inv;
    }
    __syncthreads();

    // ---- pw head-mix (in place) ----
    for (int p = tid; p < 2401; p += 384) {
        int m = p / 49, n = p - m * 49;
        float a[6];
        #pragma unroll
        for (int g2 = 0; g2 < 6; g2++) a[g2] = ATT[g2][m][n];
        #pragma unroll
        for (int g2 = 0; g2 < 6; g2++) {
            float v = pwb[g2];
            #pragma unroll
            for (int h2 = 0; h2 < 6; h2++) v += a[h2] * pww[h2 * 6 + g2];
            ATT[g2][m][n] = v;
        }
    }
    __syncthreads();

    // ---- PV (per head) + spatial scatter epilogue ----
    f32x4 oa[4][2];
    #pragma unroll
    for (int mi = 0; mi < 4; mi++)
        #pragma unroll
        for (int ni = 0; ni < 2; ni++) oa[mi][ni] = (f32x4){0.f, 0.f, 0.f, 0.f};
    #pragma unroll
    for (int kst = 0; kst < 2; kst++) {
        #pragma unroll
        for (int mi = 0; mi < 4; mi++) {
            int m = mi * 16 + (lane & 15); if (m > 48) m = 48;
            const float* ap = &ATT[h][m][kst * 32 + ((lane >> 4) << 3)];
            bf16x8 afr;
            #pragma unroll
            for (int j = 0; j < 8; j++) afr[j] = (short)f2bf(ap[j]);
            #pragma unroll
            for (int ni = 0; ni < 2; ni++)
                oa[mi][ni] = __builtin_amdgcn_mfma_f32_16x16x32_bf16(afr, vfr[kst][ni], oa[mi][ni], 0, 0, 0);
        }
    }
    int bb = w >> 6;
    #pragma unroll
    for (int mi = 0; mi < 4; mi++)
        #pragma unroll
        for (int ni = 0; ni < 2; ni++)
            #pragma unroll
            for (int r = 0; r < 4; r++) {
                int m = mi * 16 + ((lane >> 4) << 2) + r, d = ni * 16 + (lane & 15);
                if (m < 49) {
                    int rr = m / 7, ss = m - rr * 7;
                    int ho = wi * 7 + rr + 3; if (ho >= 56) ho -= 56;     // roll(+SHIFT)
                    int wo = wj * 7 + ss + 3; if (wo >= 56) wo -= 56;
                    long tp = ((long)(bb * 56 + ho) * 56 + wo);
                    aout[tp * 192 + h * 32 + d] = f2bf(oa[mi][ni][r]);
                }
            }
}

// ---------------- launcher ----------------
extern "C" void kernel_launch(void* const* d_in, const int* in_sizes, int n_in,
                              void* d_out, int out_size, void* d_ws, size_t ws_size,
                              hipStream_t stream)
{
    const float* x      = (const float*)d_in[0];
    const float* n1g    = (const float*)d_in[1];
    const float* n1b    = (const float*)d_in[2];
    const float* qkv_w  = (const float*)d_in[3];
    const float* qkv_b  = (const float*)d_in[4];
    const float* proj_w = (const float*)d_in[5];
    const float* proj_b = (const float*)d_in[6];
    const float* rpb    = (const float*)d_in[7];
    const float* pl_w   = (const float*)d_in[8];
    const float* pl_b   = (const float*)d_in[9];
    const float* pw_w   = (const float*)d_in[10];
    const float* pw_b   = (const float*)d_in[11];
    const float* n2g    = (const float*)d_in[12];
    const float* n2b    = (const float*)d_in[13];
    const float* fc1_w  = (const float*)d_in[14];
    const float* fc1_b  = (const float*)d_in[15];
    const float* fc2_w  = (const float*)d_in[16];
    const float* fc2_b  = (const float*)d_in[17];

    float* out   = (float*)d_out;   // f32: [xo | q | k | v], each OUTCH elements
    float* out_q = out + OUTCH;
    float* out_k = out + 2 * OUTCH;
    float* out_v = out + 3 * OUTCH;

    // ws: bufT 38,535,168 (bf16 TOKx192, time-shared attn-out(spatial)/h2) | bufW 884,736
    char* ws = (char*)d_ws;
    unsigned short* bufT = (unsigned short*)ws;
    unsigned short* bufW = (unsigned short*)(ws + 38535168);

    k_prep_w<<<1728, 256, 0, stream>>>(qkv_w, proj_w, fc1_w, fc2_w, bufW);
    k_qkv<<<dim3(3, 1568), 256, 0, stream>>>(x, n1g, n1b, bufW, qkv_b, out_q);
    k_attn<<<NWIN, 384, 0, stream>>>(out_q, out_k, out_v,
                                     rpb, pl_w, pl_b, pw_w, pw_b, bufT);      // bufT = attn out (spatial)
    k_proj<<<1568, 256, 0, stream>>>(bufT, bufW + 110592, proj_b, x, n2g, n2b,
                                     out, bufT);                              // xo f32 + h2 in-place
    k_mlp<<<1568, 256, 0, stream>>>(bufT, bufW + 147456, fc1_b, bufW + 294912, fc2_b, out);
}